// Round 9
// baseline (750.448 us; speedup 1.0000x reference)
//
#include <hip/hip_runtime.h>
#include <hip/hip_bf16.h>
#include <stdint.h>

// Encoder: X->(transpose)->QKV GEMMs -> attention(softmax) -> Wx GEMM -> 128-step LSTM
// B=512 T=128 N=256 H=256, all inputs f32, output f32 (B,T,H).
// Round 9: second resubmit of the tagged-data-sync LSTM (rounds 7 & 8 both died of
// infra 'UnresponsiveContainer' on the same dead pod, pre-push). Poll loop now has a
// huge safety bound + s_sleep back-off: a pathological stall fails absmax instead of
// wedging the container. Semantics otherwise identical to the audited round-7 design.

#define DI __device__ __forceinline__

typedef __attribute__((ext_vector_type(8))) short bf16x8;   // 8 bf16 = 4 VGPR (MFMA A/B frag)
typedef __attribute__((ext_vector_type(4))) short short4v;  // 8B
typedef __attribute__((ext_vector_type(4))) float f32x4;    // MFMA C/D frag
typedef __attribute__((ext_vector_type(4))) int int4v;      // 16B

union U8 { bf16x8 v; short4v h[2]; int4v i; };

DI unsigned short f2bf(float x){
  union { float f; unsigned u; } v; v.f = x;
  unsigned r = v.u + 0x7fffu + ((v.u >> 16) & 1u);
  return (unsigned short)(r >> 16);
}
DI float bf2f(unsigned short x){
  union { unsigned u; float f; } v; v.u = ((unsigned)x) << 16; return v.f;
}
DI float rcp_(float x){ return __builtin_amdgcn_rcpf(x); }
DI float sigm(float x){ return rcp_(1.0f + __expf(-x)); }
DI float tanhf_(float x){ return 1.0f - 2.0f * rcp_(1.0f + __expf(2.0f * x)); }

#define BB 512
#define TT 128
#define NN 256
#define HH 256

// ---------------------------------------------------------------------------
// K0: cast weights to bf16, fuse biases, zero the tagged h-exchange buffer
__global__ void k_prep(const float* __restrict__ Wq, const float* __restrict__ Wk,
                       const float* __restrict__ Wv, const float* __restrict__ Wih,
                       const float* __restrict__ bih, const float* __restrict__ bhh,
                       unsigned short* __restrict__ wqb, unsigned short* __restrict__ wkb,
                       unsigned short* __restrict__ wvb, unsigned short* __restrict__ wihb,
                       float* __restrict__ bias, unsigned long long* __restrict__ hbuf){
  int i = blockIdx.x * 256 + threadIdx.x;
  if (i < 16384){ wqb[i] = f2bf(Wq[i]); wkb[i] = f2bf(Wk[i]); wvb[i] = f2bf(Wv[i]); }
  if (i < 262144){ wihb[i] = f2bf(Wih[i]); hbuf[i] = 0ULL; }
  if (i < 1024){ bias[i] = bih[i] + bhh[i]; }
}

// K0b: W_hh -> fragment-major bf16: frag (j, kk, g) holds
// W[j][kk*32+4g+{0..3}] , W[j][kk*32+16+4g+{0..3}].  Byte = j*512 + kk*64 + g*16.
__global__ void k_prep2(const float* __restrict__ Whh, unsigned short* __restrict__ whh_f){
  int idx = blockIdx.x * 256 + threadIdx.x;   // 8192 = 1024 j x 8 kk
  int j = idx >> 3, kk = idx & 7;
  const float* src = Whh + j * 256 + kk * 32;
  unsigned short o[32];
  #pragma unroll
  for (int g = 0; g < 4; ++g)
    #pragma unroll
    for (int e = 0; e < 4; ++e){
      o[g * 8 + e]     = f2bf(src[4 * g + e]);
      o[g * 8 + 4 + e] = f2bf(src[16 + 4 * g + e]);
    }
  int4v* dst = (int4v*)((char*)whh_f + j * 512 + kk * 64);
  #pragma unroll
  for (int q = 0; q < 4; ++q) dst[q] = *(int4v*)(o + q * 8);
}

// ---------------------------------------------------------------------------
// K1: X (B,T,N) f32 -> Xp (B,N,T) bf16   (tile transpose through LDS)
__global__ __launch_bounds__(256) void k_xpose(const float* __restrict__ X,
                                               unsigned short* __restrict__ Xp){
  __shared__ float tile[128][65];
  int b = blockIdx.y, n0 = blockIdx.x * 64;
  int tid = threadIdx.x;
  int nloc = tid & 63, t0 = tid >> 6;
  const float* src = X + (size_t)b * TT * NN + n0 + nloc;
  #pragma unroll
  for (int r = 0; r < 32; ++r){
    int t = r * 4 + t0;
    tile[t][nloc] = src[(size_t)t * NN];
  }
  __syncthreads();
  int tl = tid & 127, nr0 = tid >> 7;
  unsigned short* dst = Xp + ((size_t)b * NN + n0) * TT + tl;
  #pragma unroll
  for (int r = 0; r < 32; ++r){
    int n = r * 2 + nr0;
    dst[(size_t)n * TT] = f2bf(tile[tl][n]);
  }
}

// ---------------------------------------------------------------------------
// K2: Q/K/V = Xp @ W^T per batch.  M=131072 rows, N=128, K=128.  blockIdx.y = mode.
__global__ __launch_bounds__(256) void k_qkv(const unsigned short* __restrict__ Xp,
      const unsigned short* __restrict__ Wqb, const unsigned short* __restrict__ Wkb,
      const unsigned short* __restrict__ Wvb,
      unsigned short* __restrict__ Qo, unsigned short* __restrict__ Ko,
      unsigned short* __restrict__ Vo){
  __shared__ __align__(16) char smem[32768 + 8192];
  unsigned short* Bs = (unsigned short*)smem;
  char* As = smem + 32768;
  char* Os = smem;
  int mode = blockIdx.y;
  const unsigned short* W = (mode == 0) ? Wqb : ((mode == 1) ? Wkb : Wvb);
  int m0 = blockIdx.x * 128;
  int tid = threadIdx.x;

  #pragma unroll
  for (int it = 0; it < 16; ++it){
    int c = it * 256 + tid;
    int j = c >> 5;
    int kc = (c & 31) << 2;
    short4v v = *(const short4v*)(W + j * 128 + kc);
    *(short4v*)((char*)Bs + j * 256 + ((kc * 2) ^ ((j & 7) << 4))) = v;
  }

  int lane = tid & 63, wv = tid >> 6;
  int wr = wv >> 1, wc = wv & 1;
  int l15 = lane & 15, g = lane >> 4;
  f32x4 zro = {0.f, 0.f, 0.f, 0.f};
  f32x4 acc[4][4];
  #pragma unroll
  for (int a = 0; a < 4; ++a)
    #pragma unroll
    for (int bq = 0; bq < 4; ++bq) acc[a][bq] = zro;

  int arow = tid >> 1, ahalf = (tid & 1) * 16;
  const unsigned short* Ap = Xp + (size_t)(m0 + arow) * 128;

  for (int ks = 0; ks < 4; ++ks){
    __syncthreads();
    {
      const unsigned short* s = Ap + ks * 32 + ahalf;
      char* base = As + arow * 64;
      int kb = ahalf * 2;
      int sw = (arow & 7) << 3;
      *(short4v*)(base + ((kb     ) ^ sw)) = *(const short4v*)(s);
      *(short4v*)(base + ((kb +  8) ^ sw)) = *(const short4v*)(s + 4);
      *(short4v*)(base + ((kb + 16) ^ sw)) = *(const short4v*)(s + 8);
      *(short4v*)(base + ((kb + 24) ^ sw)) = *(const short4v*)(s + 12);
    }
    __syncthreads();
    U8 af[4];
    #pragma unroll
    for (int mt = 0; mt < 4; ++mt){
      int ar = wr * 64 + mt * 16 + l15;
      const char* ab = As + ar * 64;
      int sw = (ar & 7) << 3;
      af[mt].h[0] = *(const short4v*)(ab + ((8 * g) ^ sw));
      af[mt].h[1] = *(const short4v*)(ab + ((8 * g + 32) ^ sw));
    }
    #pragma unroll
    for (int nt = 0; nt < 4; ++nt){
      int jr = wc * 64 + nt * 16 + l15;
      const char* bb = (const char*)Bs + jr * 256;
      int kb = ks * 64 + 8 * g, sw = (jr & 7) << 4;
      U8 bf;
      bf.h[0] = *(const short4v*)(bb + (kb ^ sw));
      bf.h[1] = *(const short4v*)(bb + ((kb + 32) ^ sw));
      #pragma unroll
      for (int mt = 0; mt < 4; ++mt)
        acc[mt][nt] = __builtin_amdgcn_mfma_f32_16x16x32_bf16(af[mt].v, bf.v, acc[mt][nt], 0, 0, 0);
    }
  }
  __syncthreads();
  float scale = (mode == 0) ? 0.0625f : 1.0f;
  #pragma unroll
  for (int mt = 0; mt < 4; ++mt)
    #pragma unroll
    for (int nt = 0; nt < 4; ++nt)
      #pragma unroll
      for (int r = 0; r < 4; ++r){
        int row = wr * 64 + mt * 16 + g * 4 + r;
        int col = wc * 64 + nt * 16 + l15;
        unsigned short hv = f2bf(acc[mt][nt][r] * scale);
        int addr = (mode == 2) ? (col * 256 + ((row * 2) ^ ((col & 7) << 4)))
                               : (row * 256 + ((col * 2) ^ ((row & 7) << 4)));
        *(unsigned short*)(Os + addr) = hv;
      }
  __syncthreads();
  int orow = tid >> 1, oseg = tid & 1;
  const char* srcrow = Os + orow * 256;
  unsigned short* dst;
  if (mode == 2){
    int bq = m0 >> 8, ibase = m0 & 255;
    dst = Vo + ((size_t)bq * 128 + orow) * 256 + ibase + oseg * 64;
  } else {
    dst = ((mode == 0) ? Qo : Ko) + (size_t)(m0 + orow) * 128 + oseg * 64;
  }
  #pragma unroll
  for (int c = 0; c < 8; ++c){
    int kb = oseg * 128 + c * 16;
    *(int4v*)((char*)dst + c * 16) = *(const int4v*)(srcrow + (kb ^ ((orow & 7) << 4)));
  }
}

// ---------------------------------------------------------------------------
// K3: fused attention per (b, 64-row i-tile). S=QK^T, softmax, Xa^T = V^T P^T.
__global__ __launch_bounds__(256) void k_attn(const unsigned short* __restrict__ Q,
        const unsigned short* __restrict__ K, const unsigned short* __restrict__ Vt,
        unsigned short* __restrict__ Xa){
  __shared__ __align__(16) char smem[16384 + 65536 + 32768 + 256];
  char* Qs = smem;
  char* Ks = smem + 16384;
  char* Ps = smem + 16384 + 65536;
  float* rden = (float*)(smem + 16384 + 65536 + 32768);
  int b = blockIdx.y, i0 = blockIdx.x * 64;
  int tid = threadIdx.x, lane = tid & 63, wv = tid >> 6;
  int l15 = lane & 15, g = lane >> 4;

  {
    int row = tid >> 2, q = tid & 3;
    const char* src = (const char*)(Q + ((size_t)b * 256 + i0 + row) * 128) + q * 64;
    char* dstr = Qs + row * 256;
    int sw = (row & 7) << 4;
    #pragma unroll
    for (int c = 0; c < 4; ++c){
      int kb = q * 64 + c * 16;
      *(int4v*)(dstr + (kb ^ sw)) = *(const int4v*)(src + c * 16);
    }
  }
  {
    const char* src = (const char*)(K + ((size_t)b * 256 + tid) * 128);
    char* dstr = Ks + tid * 256;
    int sw = (tid & 7) << 4;
    #pragma unroll
    for (int c = 0; c < 16; ++c)
      *(int4v*)(dstr + ((c * 16) ^ sw)) = *(const int4v*)(src + c * 16);
  }
  __syncthreads();

  f32x4 zro = {0.f, 0.f, 0.f, 0.f};
  f32x4 acc[16];
  #pragma unroll
  for (int nt = 0; nt < 16; ++nt) acc[nt] = zro;
  #pragma unroll
  for (int kk = 0; kk < 4; ++kk){
    int ar = wv * 16 + l15;
    const char* ab = Qs + ar * 256;
    int kb = kk * 64 + 8 * g, swa = (ar & 7) << 4;
    U8 a;
    a.h[0] = *(const short4v*)(ab + (kb ^ swa));
    a.h[1] = *(const short4v*)(ab + ((kb + 32) ^ swa));
    #pragma unroll
    for (int nt = 0; nt < 16; ++nt){
      int jr = nt * 16 + l15;
      const char* bb = Ks + jr * 256;
      int swb = (jr & 7) << 4;
      U8 bf;
      bf.h[0] = *(const short4v*)(bb + (kb ^ swb));
      bf.h[1] = *(const short4v*)(bb + ((kb + 32) ^ swb));
      acc[nt] = __builtin_amdgcn_mfma_f32_16x16x32_bf16(a.v, bf.v, acc[nt], 0, 0, 0);
    }
  }
  float mx[4], sm[4];
  #pragma unroll
  for (int r = 0; r < 4; ++r){
    float m = acc[0][r];
    #pragma unroll
    for (int nt = 1; nt < 16; ++nt) m = fmaxf(m, acc[nt][r]);
    #pragma unroll
    for (int s = 1; s < 16; s <<= 1) m = fmaxf(m, __shfl_xor(m, s));
    mx[r] = m;
  }
  #pragma unroll
  for (int r = 0; r < 4; ++r){
    float s = 0.f;
    #pragma unroll
    for (int nt = 0; nt < 16; ++nt){
      float p = __expf(acc[nt][r] - mx[r]);
      acc[nt][r] = p; s += p;
    }
    #pragma unroll
    for (int sd = 1; sd < 16; sd <<= 1) s += __shfl_xor(s, sd);
    sm[r] = s;
  }
  #pragma unroll
  for (int nt = 0; nt < 16; ++nt)
    #pragma unroll
    for (int r = 0; r < 4; ++r){
      int ir = wv * 16 + g * 4 + r;
      *(unsigned short*)(Ps + ir * 512 + ((nt * 16 + l15) * 2 ^ ((ir & 7) << 4))) = f2bf(acc[nt][r]);
    }
  #pragma unroll
  for (int r = 0; r < 4; ++r)
    if (l15 == r) rden[wv * 16 + g * 4 + r] = rcp_(sm[r]);
  __syncthreads();
  {
    int row = tid >> 1, half = tid & 1;
    const char* src = (const char*)(Vt + ((size_t)b * 128 + row) * 256) + half * 256;
    char* dstr = Ks + row * 512;
    int sw = (row & 7) << 4;
    #pragma unroll
    for (int c = 0; c < 16; ++c){
      int jb = half * 256 + c * 16;
      *(int4v*)(dstr + (jb ^ sw)) = *(const int4v*)(src + c * 16);
    }
  }
  __syncthreads();

  f32x4 acc2[2][4];
  #pragma unroll
  for (int mt = 0; mt < 2; ++mt)
    #pragma unroll
    for (int nt = 0; nt < 4; ++nt) acc2[mt][nt] = zro;
  #pragma unroll
  for (int kk = 0; kk < 8; ++kk){
    int kb = kk * 64 + 8 * g;
    U8 bfr[4];
    #pragma unroll
    for (int nt = 0; nt < 4; ++nt){
      int ir = nt * 16 + l15;
      const char* pb = Ps + ir * 512;
      int sw = (ir & 7) << 4;
      bfr[nt].h[0] = *(const short4v*)(pb + (kb ^ sw));
      bfr[nt].h[1] = *(const short4v*)(pb + ((kb + 32) ^ sw));
    }
    #pragma unroll
    for (int mt = 0; mt < 2; ++mt){
      int tr = wv * 32 + mt * 16 + l15;
      const char* ab = Ks + tr * 512;
      int sw = (tr & 7) << 4;
      U8 a;
      a.h[0] = *(const short4v*)(ab + (kb ^ sw));
      a.h[1] = *(const short4v*)(ab + ((kb + 32) ^ sw));
      #pragma unroll
      for (int nt = 0; nt < 4; ++nt)
        acc2[mt][nt] = __builtin_amdgcn_mfma_f32_16x16x32_bf16(a.v, bfr[nt].v, acc2[mt][nt], 0, 0, 0);
    }
  }
  #pragma unroll
  for (int nt = 0; nt < 4; ++nt){
    float rd = rden[nt * 16 + l15];
    #pragma unroll
    for (int mt = 0; mt < 2; ++mt)
      #pragma unroll
      for (int r = 0; r < 4; ++r){
        int t = wv * 32 + mt * 16 + g * 4 + r;
        int i = i0 + nt * 16 + l15;
        Xa[((size_t)b * 128 + t) * 256 + i] = f2bf(acc2[mt][nt][r] * rd);
      }
  }
}

// ---------------------------------------------------------------------------
// K4: Wx = Xa @ W_ih^T + bias, written time-major (T,B,4H).
template<bool WXF32>
__global__ __launch_bounds__(256) void k_wx(const unsigned short* __restrict__ Xa,
        const unsigned short* __restrict__ Wih, const float* __restrict__ bias,
        void* __restrict__ WxT){
  __shared__ __align__(16) char smem[65536 + 8192];
  char* Bsm = smem;
  char* As = smem + 65536;
  int bidx = blockIdx.x;
  int j0 = blockIdx.y * 128;
  int tid = threadIdx.x;
  {
    int row = tid >> 1, half = tid & 1;
    const char* src = (const char*)(Wih + (size_t)(j0 + row) * 256) + half * 256;
    char* dstr = Bsm + row * 512;
    int sw = (row & 7) << 4;
    #pragma unroll
    for (int c = 0; c < 16; ++c){
      int kb = half * 256 + c * 16;
      *(int4v*)(dstr + (kb ^ sw)) = *(const int4v*)(src + c * 16);
    }
  }
  int lane = tid & 63, wv = tid >> 6, wr = wv >> 1, wc = wv & 1;
  int l15 = lane & 15, g = lane >> 4;
  f32x4 zro = {0.f, 0.f, 0.f, 0.f};
  f32x4 acc[4][4];
  #pragma unroll
  for (int a = 0; a < 4; ++a)
    #pragma unroll
    for (int bq = 0; bq < 4; ++bq) acc[a][bq] = zro;
  int arow = tid >> 1, ahalf = (tid & 1) * 16;
  const unsigned short* Ap = Xa + (size_t)(bidx * 128 + arow) * 256;
  for (int ks = 0; ks < 8; ++ks){
    __syncthreads();
    {
      const unsigned short* s = Ap + ks * 32 + ahalf;
      char* base = As + arow * 64;
      int kb = ahalf * 2, sw = (arow & 7) << 3;
      *(short4v*)(base + ((kb     ) ^ sw)) = *(const short4v*)(s);
      *(short4v*)(base + ((kb +  8) ^ sw)) = *(const short4v*)(s + 4);
      *(short4v*)(base + ((kb + 16) ^ sw)) = *(const short4v*)(s + 8);
      *(short4v*)(base + ((kb + 24) ^ sw)) = *(const short4v*)(s + 12);
    }
    __syncthreads();
    U8 af[4];
    #pragma unroll
    for (int mt = 0; mt < 4; ++mt){
      int ar = wr * 64 + mt * 16 + l15;
      const char* ab = As + ar * 64;
      int sw = (ar & 7) << 3;
      af[mt].h[0] = *(const short4v*)(ab + ((8 * g) ^ sw));
      af[mt].h[1] = *(const short4v*)(ab + ((8 * g + 32) ^ sw));
    }
    #pragma unroll
    for (int nt = 0; nt < 4; ++nt){
      int jr = wc * 64 + nt * 16 + l15;
      const char* bb = Bsm + jr * 512;
      int kb = ks * 64 + 8 * g, sw = (jr & 7) << 4;
      U8 bf;
      bf.h[0] = *(const short4v*)(bb + (kb ^ sw));
      bf.h[1] = *(const short4v*)(bb + ((kb + 32) ^ sw));
      #pragma unroll
      for (int mt = 0; mt < 4; ++mt)
        acc[mt][nt] = __builtin_amdgcn_mfma_f32_16x16x32_bf16(af[mt].v, bf.v, acc[mt][nt], 0, 0, 0);
    }
  }
  #pragma unroll
  for (int nt = 0; nt < 4; ++nt){
    int j = j0 + wc * 64 + nt * 16 + l15;
    float bs = bias[j];
    #pragma unroll
    for (int mt = 0; mt < 4; ++mt)
      #pragma unroll
      for (int r = 0; r < 4; ++r){
        int t = wr * 64 + mt * 16 + g * 4 + r;
        float v = acc[mt][nt][r] + bs;
        size_t o = ((size_t)t * 512 + bidx) * 1024 + j;
        if (WXF32) ((float*)WxT)[o] = v;
        else       ((unsigned short*)WxT)[o] = f2bf(v);
      }
  }
}

// ---------------------------------------------------------------------------
// K5 v6: LSTM, group-sharded W, tagged-data sync.
// 256 blocks x 512 thr; group of 4 blocks = 8 batches; member m owns cols [64m,64m+64).
// Publish h as {tag=t+1, hi|lo} u64 (relaxed system atomics), readers poll the data
// directly (bounded spin + s_sleep back-off). hbuf zeroed by k_prep each launch.
template<bool WXF32>
__global__ __launch_bounds__(512, 2) void k_lstm6(const void* __restrict__ WxT,
        const unsigned short* __restrict__ whh_f, float* __restrict__ out,
        unsigned long long* __restrict__ hbuf){
  __shared__ __align__(16) char smem[8192 + 8448];
  char* HS = smem;                    // A-layout h: [row16][k256 bf16], XOR (row&7)<<3
  float* GS = (float*)(smem + 8192);  // gate stage: [batch][gate][col], stride 264/batch
  int tid = threadIdx.x, lane = tid & 63, wv = tid >> 6;
  int l15 = lane & 15, g = lane >> 4;
  int bid = blockIdx.x;
  int x = bid & 7, q = bid >> 3;          // same-XCD grouping heuristic (bid mod 8)
  int y = q >> 2, m = q & 3;
  int grp = y * 8 + x;                    // [0,64)
  int b0 = grp * 8;
  int c0 = m * 64;
  int tb = tid >> 6, tc = tid & 63;       // gate-phase (batch, col_local)

  // ---- W slice into registers: wave w owns j_local [32w, 32w+32)
  U8 breg[2][8];
  #pragma unroll
  for (int nt = 0; nt < 2; ++nt){
    int jl = wv * 32 + nt * 16 + l15;
    int jg = (jl >> 6) * 256 + c0 + (jl & 63);
    #pragma unroll
    for (int kk = 0; kk < 8; ++kk)
      breg[nt][kk].i = *(const int4v*)((const char*)whh_f + (size_t)jg * 512 + kk * 64 + g * 16);
  }
  { int4v z = {0,0,0,0}; *(int4v*)(HS + tid * 16) = z; }   // h(=0) for t=0
  float cst = 0.f;
  __syncthreads();

  // Wx for t=0
  float wx[4];
  {
    size_t ob = ((size_t)b0 + tb) * 1024 + c0 + tc;
    #pragma unroll
    for (int gate = 0; gate < 4; ++gate)
      wx[gate] = WXF32 ? ((const float*)WxT)[ob + gate * 256]
                       : bf2f(((const unsigned short*)WxT)[ob + gate * 256]);
  }

  int swA = (l15 & 7) << 3;
  const char* hsrow = HS + l15 * 512;
  int keep = g >> 1;
  #pragma unroll 1
  for (int t = 0; t < 128; ++t){
    // ---- matmul: acc[2] = h(hi/lo 16 rows) @ Wslice
    f32x4 zro = {0.f, 0.f, 0.f, 0.f};
    f32x4 acc[2] = {zro, zro};
    #pragma unroll
    for (int kk = 0; kk < 8; ++kk){
      U8 a;
      a.h[0] = *(const short4v*)(hsrow + ((kk * 64 + 8 * g) ^ swA));
      a.h[1] = *(const short4v*)(hsrow + ((kk * 64 + 32 + 8 * g) ^ swA));
      acc[0] = __builtin_amdgcn_mfma_f32_16x16x32_bf16(a.v, breg[0][kk].v, acc[0], 0, 0, 0);
      acc[1] = __builtin_amdgcn_mfma_f32_16x16x32_bf16(a.v, breg[1][kk].v, acc[1], 0, 0, 0);
    }
    // ---- fold hi+lo (keep own nt, send the other; partner g^2 holds the other rows)
    #pragma unroll
    for (int r = 0; r < 4; ++r){
      float v0 = acc[0][r], v1 = acc[1][r];
      float kv = keep ? v1 : v0;
      float sv = keep ? v0 : v1;
      float val = kv + __shfl_xor(sv, 32);
      int jl = wv * 32 + keep * 16 + l15;
      int batch = (g & 1) * 4 + r;
      GS[batch * 264 + (jl >> 6) * 66 + (jl & 63)] = val;   // conflict-free layout
    }
    __syncthreads();
    // ---- gate phase: thread owns (tb, tc); 4 conflict-free b32 reads
    float gv0 = GS[tb * 264 +   0 + tc];
    float gv1 = GS[tb * 264 +  66 + tc];
    float gv2 = GS[tb * 264 + 132 + tc];
    float gv3 = GS[tb * 264 + 198 + tc];
    // prefetch Wx(t+1) — latency hides under publish/poll
    float wxn[4] = {0.f, 0.f, 0.f, 0.f};
    if (t < 127){
      size_t ob = ((size_t)(t + 1) * 512 + b0 + tb) * 1024 + c0 + tc;
      #pragma unroll
      for (int gate = 0; gate < 4; ++gate)
        wxn[gate] = WXF32 ? ((const float*)WxT)[ob + gate * 256]
                          : bf2f(((const unsigned short*)WxT)[ob + gate * 256]);
    }
    float gi = sigm(gv0 + wx[0]);
    float gf = sigm(gv1 + wx[1]);
    float gg = tanhf_(gv2 + wx[2]);
    float go = sigm(gv3 + wx[3]);
    float c = gf * cst + gi * gg;
    cst = c;
    float h = go * tanhf_(c);
    out[((size_t)(b0 + tb) * 128 + t) * 256 + c0 + tc] = h;
    if (t < 127){
      // ---- publish own (batch, col) as tagged u64: {tag=t+1, hi|lo}
      unsigned short hhi = f2bf(h);
      unsigned short hlo = f2bf(h - bf2f(hhi));
      unsigned int pk = (unsigned int)hhi | ((unsigned int)hlo << 16);
      unsigned long long* hb = hbuf + ((size_t)grp * 2 + (t & 1)) * 2048;
      __hip_atomic_store(hb + tb * 256 + c0 + tc,
                         ((unsigned long long)(t + 1) << 32) | (unsigned long long)pk,
                         __ATOMIC_RELAXED, __HIP_MEMORY_SCOPE_SYSTEM);
      // ---- poll the data itself (tags embedded). Bounded spin: a pathological
      // stall fails absmax instead of wedging the GPU/container.
      {
        int bb = tid >> 6, cg = tid & 63;          // this thread reloads (bb, cols cg*4..+3)
        unsigned long long* sp = hb + bb * 256 + cg * 4;
        unsigned long long w0, w1, w2, w3;
        unsigned int want = (unsigned int)(t + 1);
        for (int it = 0; it < (1 << 27); ++it){
          w0 = __hip_atomic_load(sp,     __ATOMIC_RELAXED, __HIP_MEMORY_SCOPE_SYSTEM);
          w1 = __hip_atomic_load(sp + 1, __ATOMIC_RELAXED, __HIP_MEMORY_SCOPE_SYSTEM);
          w2 = __hip_atomic_load(sp + 2, __ATOMIC_RELAXED, __HIP_MEMORY_SCOPE_SYSTEM);
          w3 = __hip_atomic_load(sp + 3, __ATOMIC_RELAXED, __HIP_MEMORY_SCOPE_SYSTEM);
          if ((unsigned int)(w0 >> 32) == want && (unsigned int)(w1 >> 32) == want &&
              (unsigned int)(w2 >> 32) == want && (unsigned int)(w3 >> 32) == want) break;
          __builtin_amdgcn_s_sleep(1);
        }
        unsigned int u0 = (unsigned int)w0, u1 = (unsigned int)w1;
        unsigned int u2 = (unsigned int)w2, u3 = (unsigned int)w3;
        short4v hiv = { (short)(u0 & 0xffff), (short)(u1 & 0xffff),
                        (short)(u2 & 0xffff), (short)(u3 & 0xffff) };
        short4v lov = { (short)(u0 >> 16), (short)(u1 >> 16),
                        (short)(u2 >> 16), (short)(u3 >> 16) };
        int sw = (bb & 7) << 3;
        int cb = (cg * 8) ^ sw;
        *(short4v*)(HS + bb * 512 + cb) = hiv;
        *(short4v*)(HS + (bb + 8) * 512 + cb) = lov;
      }
      __syncthreads();
      wx[0] = wxn[0]; wx[1] = wxn[1]; wx[2] = wxn[2]; wx[3] = wxn[3];
    }
  }
}

// ---------------------------------------------------------------------------
extern "C" void kernel_launch(void* const* d_in, const int* in_sizes, int n_in,
                              void* d_out, int out_size, void* d_ws, size_t ws_size,
                              hipStream_t stream){
  (void)in_sizes; (void)n_in; (void)out_size;
  const float* X   = (const float*)d_in[0];
  const float* Wq  = (const float*)d_in[1];
  const float* Wk  = (const float*)d_in[2];
  const float* Wv  = (const float*)d_in[3];
  const float* Wih = (const float*)d_in[4];
  const float* Whh = (const float*)d_in[5];
  const float* bih = (const float*)d_in[6];
  const float* bhh = (const float*)d_in[7];
  float* out = (float*)d_out;
  char* ws = (char*)d_ws;

  const size_t SZ  = 33554432ULL;        // one (B,N,T) bf16 buffer
  const size_t WXF = 268435456ULL;       // Wx f32 (T,B,4H)
  const size_t WTS = 3300000ULL;         // casted weights + bias + hbuf
  bool wxf32 = ws_size >= WXF + SZ + WTS;
  size_t wxb = wxf32 ? WXF : WXF / 2;

  unsigned short* p_xp = (unsigned short*)ws;
  unsigned short* p_q  = (unsigned short*)(ws + SZ);
  unsigned short* p_k  = (unsigned short*)(ws + 2 * SZ);
  unsigned short* p_vt = (unsigned short*)(ws + 3 * SZ);
  void* p_wx = (void*)ws;
  char* p = ws + wxb;
  unsigned short* p_xa  = (unsigned short*)p; p += 33554432;
  unsigned short* p_wqb = (unsigned short*)p; p += 32768;
  unsigned short* p_wkb = (unsigned short*)p; p += 32768;
  unsigned short* p_wvb = (unsigned short*)p; p += 32768;
  unsigned short* p_wihb= (unsigned short*)p; p += 524288;
  unsigned short* p_whhf= (unsigned short*)p; p += 524288;
  float* p_bias = (float*)p; p += 4096;
  unsigned long long* p_hbuf = (unsigned long long*)p;   // 2 MB (64 grp x 2 x 2048 u64)

  k_prep<<<1024, 256, 0, stream>>>(Wq, Wk, Wv, Wih, bih, bhh,
                                   p_wqb, p_wkb, p_wvb, p_wihb, p_bias, p_hbuf);
  k_prep2<<<32, 256, 0, stream>>>(Whh, p_whhf);
  k_xpose<<<dim3(4, 512), 256, 0, stream>>>(X, p_xp);
  k_qkv<<<dim3(1024, 3), 256, 0, stream>>>(p_xp, p_wqb, p_wkb, p_wvb, p_q, p_k, p_vt);
  k_attn<<<dim3(4, 512), 256, 0, stream>>>(p_q, p_k, p_vt, p_xa);
  if (wxf32){
    k_wx<true><<<dim3(512, 8), 256, 0, stream>>>(p_xa, p_wihb, p_bias, p_wx);
    k_lstm6<true><<<256, 512, 0, stream>>>(p_wx, p_whhf, out, p_hbuf);
  } else {
    k_wx<false><<<dim3(512, 8), 256, 0, stream>>>(p_xa, p_wihb, p_bias, p_wx);
    k_lstm6<false><<<256, 512, 0, stream>>>(p_wx, p_whhf, out, p_hbuf);
  }
}

// Round 10
// 626.664 us; speedup vs baseline: 1.1975x; 1.1975x over previous
//
#include <hip/hip_runtime.h>
#include <hip/hip_bf16.h>
#include <stdint.h>

// Encoder: X->(transpose)->QKV GEMMs -> attention(softmax) -> Wx GEMM -> 128-step LSTM
// B=512 T=128 N=256 H=256, all inputs f32, output f32 (B,T,H).
// Round 10: LSTM reverted to R6's flag+drain sync (tagged-data poll regressed: 512
// pollers x 32B at the coherence point contend with the publishes — FETCH +45MB,
// WRITE +64MB, dur +130us). k_wx retiled to j-tile 256 (halves Xa re-reads).

#define DI __device__ __forceinline__

typedef __attribute__((ext_vector_type(8))) short bf16x8;   // 8 bf16 = 4 VGPR (MFMA A/B frag)
typedef __attribute__((ext_vector_type(4))) short short4v;  // 8B
typedef __attribute__((ext_vector_type(4))) float f32x4;    // MFMA C/D frag
typedef __attribute__((ext_vector_type(4))) int int4v;      // 16B

union U8 { bf16x8 v; short4v h[2]; int4v i; };

DI unsigned short f2bf(float x){
  union { float f; unsigned u; } v; v.f = x;
  unsigned r = v.u + 0x7fffu + ((v.u >> 16) & 1u);
  return (unsigned short)(r >> 16);
}
DI float bf2f(unsigned short x){
  union { unsigned u; float f; } v; v.u = ((unsigned)x) << 16; return v.f;
}
DI float rcp_(float x){ return __builtin_amdgcn_rcpf(x); }
DI float sigm(float x){ return rcp_(1.0f + __expf(-x)); }
DI float tanhf_(float x){ return 1.0f - 2.0f * rcp_(1.0f + __expf(2.0f * x)); }

#define BB 512
#define TT 128
#define NN 256
#define HH 256

// ---------------------------------------------------------------------------
// K0: cast weights to bf16, fuse biases, zero the per-member sync flags
__global__ void k_prep(const float* __restrict__ Wq, const float* __restrict__ Wk,
                       const float* __restrict__ Wv, const float* __restrict__ Wih,
                       const float* __restrict__ bih, const float* __restrict__ bhh,
                       unsigned short* __restrict__ wqb, unsigned short* __restrict__ wkb,
                       unsigned short* __restrict__ wvb, unsigned short* __restrict__ wihb,
                       float* __restrict__ bias, int* __restrict__ flags){
  int i = blockIdx.x * 256 + threadIdx.x;
  if (i < 16384){ wqb[i] = f2bf(Wq[i]); wkb[i] = f2bf(Wk[i]); wvb[i] = f2bf(Wv[i]); }
  if (i < 262144){ wihb[i] = f2bf(Wih[i]); }
  if (i < 1024){ bias[i] = bih[i] + bhh[i]; }
  if (i < 256){ flags[i] = 0; }
}

// K0b: W_hh -> fragment-major bf16: frag (j, kk, g) holds
// W[j][kk*32+4g+{0..3}] , W[j][kk*32+16+4g+{0..3}].  Byte = j*512 + kk*64 + g*16.
__global__ void k_prep2(const float* __restrict__ Whh, unsigned short* __restrict__ whh_f){
  int idx = blockIdx.x * 256 + threadIdx.x;   // 8192 = 1024 j x 8 kk
  int j = idx >> 3, kk = idx & 7;
  const float* src = Whh + j * 256 + kk * 32;
  unsigned short o[32];
  #pragma unroll
  for (int g = 0; g < 4; ++g)
    #pragma unroll
    for (int e = 0; e < 4; ++e){
      o[g * 8 + e]     = f2bf(src[4 * g + e]);
      o[g * 8 + 4 + e] = f2bf(src[16 + 4 * g + e]);
    }
  int4v* dst = (int4v*)((char*)whh_f + j * 512 + kk * 64);
  #pragma unroll
  for (int q = 0; q < 4; ++q) dst[q] = *(int4v*)(o + q * 8);
}

// ---------------------------------------------------------------------------
// K1: X (B,T,N) f32 -> Xp (B,N,T) bf16   (tile transpose through LDS)
__global__ __launch_bounds__(256) void k_xpose(const float* __restrict__ X,
                                               unsigned short* __restrict__ Xp){
  __shared__ float tile[128][65];
  int b = blockIdx.y, n0 = blockIdx.x * 64;
  int tid = threadIdx.x;
  int nloc = tid & 63, t0 = tid >> 6;
  const float* src = X + (size_t)b * TT * NN + n0 + nloc;
  #pragma unroll
  for (int r = 0; r < 32; ++r){
    int t = r * 4 + t0;
    tile[t][nloc] = src[(size_t)t * NN];
  }
  __syncthreads();
  int tl = tid & 127, nr0 = tid >> 7;
  unsigned short* dst = Xp + ((size_t)b * NN + n0) * TT + tl;
  #pragma unroll
  for (int r = 0; r < 32; ++r){
    int n = r * 2 + nr0;
    dst[(size_t)n * TT] = f2bf(tile[tl][n]);
  }
}

// ---------------------------------------------------------------------------
// K2: Q/K/V = Xp @ W^T per batch.  M=131072 rows, N=128, K=128.  blockIdx.y = mode.
__global__ __launch_bounds__(256) void k_qkv(const unsigned short* __restrict__ Xp,
      const unsigned short* __restrict__ Wqb, const unsigned short* __restrict__ Wkb,
      const unsigned short* __restrict__ Wvb,
      unsigned short* __restrict__ Qo, unsigned short* __restrict__ Ko,
      unsigned short* __restrict__ Vo){
  __shared__ __align__(16) char smem[32768 + 8192];
  unsigned short* Bs = (unsigned short*)smem;
  char* As = smem + 32768;
  char* Os = smem;
  int mode = blockIdx.y;
  const unsigned short* W = (mode == 0) ? Wqb : ((mode == 1) ? Wkb : Wvb);
  int m0 = blockIdx.x * 128;
  int tid = threadIdx.x;

  #pragma unroll
  for (int it = 0; it < 16; ++it){
    int c = it * 256 + tid;
    int j = c >> 5;
    int kc = (c & 31) << 2;
    short4v v = *(const short4v*)(W + j * 128 + kc);
    *(short4v*)((char*)Bs + j * 256 + ((kc * 2) ^ ((j & 7) << 4))) = v;
  }

  int lane = tid & 63, wv = tid >> 6;
  int wr = wv >> 1, wc = wv & 1;
  int l15 = lane & 15, g = lane >> 4;
  f32x4 zro = {0.f, 0.f, 0.f, 0.f};
  f32x4 acc[4][4];
  #pragma unroll
  for (int a = 0; a < 4; ++a)
    #pragma unroll
    for (int bq = 0; bq < 4; ++bq) acc[a][bq] = zro;

  int arow = tid >> 1, ahalf = (tid & 1) * 16;
  const unsigned short* Ap = Xp + (size_t)(m0 + arow) * 128;

  for (int ks = 0; ks < 4; ++ks){
    __syncthreads();
    {
      const unsigned short* s = Ap + ks * 32 + ahalf;
      char* base = As + arow * 64;
      int kb = ahalf * 2;
      int sw = (arow & 7) << 3;
      *(short4v*)(base + ((kb     ) ^ sw)) = *(const short4v*)(s);
      *(short4v*)(base + ((kb +  8) ^ sw)) = *(const short4v*)(s + 4);
      *(short4v*)(base + ((kb + 16) ^ sw)) = *(const short4v*)(s + 8);
      *(short4v*)(base + ((kb + 24) ^ sw)) = *(const short4v*)(s + 12);
    }
    __syncthreads();
    U8 af[4];
    #pragma unroll
    for (int mt = 0; mt < 4; ++mt){
      int ar = wr * 64 + mt * 16 + l15;
      const char* ab = As + ar * 64;
      int sw = (ar & 7) << 3;
      af[mt].h[0] = *(const short4v*)(ab + ((8 * g) ^ sw));
      af[mt].h[1] = *(const short4v*)(ab + ((8 * g + 32) ^ sw));
    }
    #pragma unroll
    for (int nt = 0; nt < 4; ++nt){
      int jr = wc * 64 + nt * 16 + l15;
      const char* bb = (const char*)Bs + jr * 256;
      int kb = ks * 64 + 8 * g, sw = (jr & 7) << 4;
      U8 bf;
      bf.h[0] = *(const short4v*)(bb + (kb ^ sw));
      bf.h[1] = *(const short4v*)(bb + ((kb + 32) ^ sw));
      #pragma unroll
      for (int mt = 0; mt < 4; ++mt)
        acc[mt][nt] = __builtin_amdgcn_mfma_f32_16x16x32_bf16(af[mt].v, bf.v, acc[mt][nt], 0, 0, 0);
    }
  }
  __syncthreads();
  float scale = (mode == 0) ? 0.0625f : 1.0f;
  #pragma unroll
  for (int mt = 0; mt < 4; ++mt)
    #pragma unroll
    for (int nt = 0; nt < 4; ++nt)
      #pragma unroll
      for (int r = 0; r < 4; ++r){
        int row = wr * 64 + mt * 16 + g * 4 + r;
        int col = wc * 64 + nt * 16 + l15;
        unsigned short hv = f2bf(acc[mt][nt][r] * scale);
        int addr = (mode == 2) ? (col * 256 + ((row * 2) ^ ((col & 7) << 4)))
                               : (row * 256 + ((col * 2) ^ ((row & 7) << 4)));
        *(unsigned short*)(Os + addr) = hv;
      }
  __syncthreads();
  int orow = tid >> 1, oseg = tid & 1;
  const char* srcrow = Os + orow * 256;
  unsigned short* dst;
  if (mode == 2){
    int bq = m0 >> 8, ibase = m0 & 255;
    dst = Vo + ((size_t)bq * 128 + orow) * 256 + ibase + oseg * 64;
  } else {
    dst = ((mode == 0) ? Qo : Ko) + (size_t)(m0 + orow) * 128 + oseg * 64;
  }
  #pragma unroll
  for (int c = 0; c < 8; ++c){
    int kb = oseg * 128 + c * 16;
    *(int4v*)((char*)dst + c * 16) = *(const int4v*)(srcrow + (kb ^ ((orow & 7) << 4)));
  }
}

// ---------------------------------------------------------------------------
// K3: fused attention per (b, 64-row i-tile). S=QK^T, softmax, Xa^T = V^T P^T.
__global__ __launch_bounds__(256) void k_attn(const unsigned short* __restrict__ Q,
        const unsigned short* __restrict__ K, const unsigned short* __restrict__ Vt,
        unsigned short* __restrict__ Xa){
  __shared__ __align__(16) char smem[16384 + 65536 + 32768 + 256];
  char* Qs = smem;
  char* Ks = smem + 16384;
  char* Ps = smem + 16384 + 65536;
  float* rden = (float*)(smem + 16384 + 65536 + 32768);
  int b = blockIdx.y, i0 = blockIdx.x * 64;
  int tid = threadIdx.x, lane = tid & 63, wv = tid >> 6;
  int l15 = lane & 15, g = lane >> 4;

  {
    int row = tid >> 2, q = tid & 3;
    const char* src = (const char*)(Q + ((size_t)b * 256 + i0 + row) * 128) + q * 64;
    char* dstr = Qs + row * 256;
    int sw = (row & 7) << 4;
    #pragma unroll
    for (int c = 0; c < 4; ++c){
      int kb = q * 64 + c * 16;
      *(int4v*)(dstr + (kb ^ sw)) = *(const int4v*)(src + c * 16);
    }
  }
  {
    const char* src = (const char*)(K + ((size_t)b * 256 + tid) * 128);
    char* dstr = Ks + tid * 256;
    int sw = (tid & 7) << 4;
    #pragma unroll
    for (int c = 0; c < 16; ++c)
      *(int4v*)(dstr + ((c * 16) ^ sw)) = *(const int4v*)(src + c * 16);
  }
  __syncthreads();

  f32x4 zro = {0.f, 0.f, 0.f, 0.f};
  f32x4 acc[16];
  #pragma unroll
  for (int nt = 0; nt < 16; ++nt) acc[nt] = zro;
  #pragma unroll
  for (int kk = 0; kk < 4; ++kk){
    int ar = wv * 16 + l15;
    const char* ab = Qs + ar * 256;
    int kb = kk * 64 + 8 * g, swa = (ar & 7) << 4;
    U8 a;
    a.h[0] = *(const short4v*)(ab + (kb ^ swa));
    a.h[1] = *(const short4v*)(ab + ((kb + 32) ^ swa));
    #pragma unroll
    for (int nt = 0; nt < 16; ++nt){
      int jr = nt * 16 + l15;
      const char* bb = Ks + jr * 256;
      int swb = (jr & 7) << 4;
      U8 bf;
      bf.h[0] = *(const short4v*)(bb + (kb ^ swb));
      bf.h[1] = *(const short4v*)(bb + ((kb + 32) ^ swb));
      acc[nt] = __builtin_amdgcn_mfma_f32_16x16x32_bf16(a.v, bf.v, acc[nt], 0, 0, 0);
    }
  }
  float mx[4], sm[4];
  #pragma unroll
  for (int r = 0; r < 4; ++r){
    float m = acc[0][r];
    #pragma unroll
    for (int nt = 1; nt < 16; ++nt) m = fmaxf(m, acc[nt][r]);
    #pragma unroll
    for (int s = 1; s < 16; s <<= 1) m = fmaxf(m, __shfl_xor(m, s));
    mx[r] = m;
  }
  #pragma unroll
  for (int r = 0; r < 4; ++r){
    float s = 0.f;
    #pragma unroll
    for (int nt = 0; nt < 16; ++nt){
      float p = __expf(acc[nt][r] - mx[r]);
      acc[nt][r] = p; s += p;
    }
    #pragma unroll
    for (int sd = 1; sd < 16; sd <<= 1) s += __shfl_xor(s, sd);
    sm[r] = s;
  }
  #pragma unroll
  for (int nt = 0; nt < 16; ++nt)
    #pragma unroll
    for (int r = 0; r < 4; ++r){
      int ir = wv * 16 + g * 4 + r;
      *(unsigned short*)(Ps + ir * 512 + ((nt * 16 + l15) * 2 ^ ((ir & 7) << 4))) = f2bf(acc[nt][r]);
    }
  #pragma unroll
  for (int r = 0; r < 4; ++r)
    if (l15 == r) rden[wv * 16 + g * 4 + r] = rcp_(sm[r]);
  __syncthreads();
  {
    int row = tid >> 1, half = tid & 1;
    const char* src = (const char*)(Vt + ((size_t)b * 128 + row) * 256) + half * 256;
    char* dstr = Ks + row * 512;
    int sw = (row & 7) << 4;
    #pragma unroll
    for (int c = 0; c < 16; ++c){
      int jb = half * 256 + c * 16;
      *(int4v*)(dstr + (jb ^ sw)) = *(const int4v*)(src + c * 16);
    }
  }
  __syncthreads();

  f32x4 acc2[2][4];
  #pragma unroll
  for (int mt = 0; mt < 2; ++mt)
    #pragma unroll
    for (int nt = 0; nt < 4; ++nt) acc2[mt][nt] = zro;
  #pragma unroll
  for (int kk = 0; kk < 8; ++kk){
    int kb = kk * 64 + 8 * g;
    U8 bfr[4];
    #pragma unroll
    for (int nt = 0; nt < 4; ++nt){
      int ir = nt * 16 + l15;
      const char* pb = Ps + ir * 512;
      int sw = (ir & 7) << 4;
      bfr[nt].h[0] = *(const short4v*)(pb + (kb ^ sw));
      bfr[nt].h[1] = *(const short4v*)(pb + ((kb + 32) ^ sw));
    }
    #pragma unroll
    for (int mt = 0; mt < 2; ++mt){
      int tr = wv * 32 + mt * 16 + l15;
      const char* ab = Ks + tr * 512;
      int sw = (tr & 7) << 4;
      U8 a;
      a.h[0] = *(const short4v*)(ab + (kb ^ sw));
      a.h[1] = *(const short4v*)(ab + ((kb + 32) ^ sw));
      #pragma unroll
      for (int nt = 0; nt < 4; ++nt)
        acc2[mt][nt] = __builtin_amdgcn_mfma_f32_16x16x32_bf16(a.v, bfr[nt].v, acc2[mt][nt], 0, 0, 0);
    }
  }
  #pragma unroll
  for (int nt = 0; nt < 4; ++nt){
    float rd = rden[nt * 16 + l15];
    #pragma unroll
    for (int mt = 0; mt < 2; ++mt)
      #pragma unroll
      for (int r = 0; r < 4; ++r){
        int t = wv * 32 + mt * 16 + g * 4 + r;
        int i = i0 + nt * 16 + l15;
        Xa[((size_t)b * 128 + t) * 256 + i] = f2bf(acc2[mt][nt][r] * rd);
      }
  }
}

// ---------------------------------------------------------------------------
// K4 v2: Wx = Xa @ W_ih^T + bias, written time-major (T,B,4H).
// j-tile 256 (grid 512x4, 512 thr, 8 waves 2x4): halves Xa logical re-reads.
template<bool WXF32>
__global__ __launch_bounds__(512) void k_wx(const unsigned short* __restrict__ Xa,
        const unsigned short* __restrict__ Wih, const float* __restrict__ bias,
        void* __restrict__ WxT){
  __shared__ __align__(16) char smem[131072 + 8192];
  char* Bsm = smem;            // 256 j-rows x 512B, swz (j&7)<<4
  char* As = smem + 131072;    // 128 x 32 bf16, 64B rows, swz (row&7)<<3
  int bidx = blockIdx.x;
  int j0 = blockIdx.y * 256;
  int tid = threadIdx.x;
  { // stage B panel once (each thread: half a row = 256B)
    int row = tid >> 1, half = tid & 1;
    const char* src = (const char*)(Wih + (size_t)(j0 + row) * 256) + half * 256;
    char* dstr = Bsm + row * 512;
    int sw = (row & 7) << 4;
    #pragma unroll
    for (int c = 0; c < 16; ++c){
      int kb = half * 256 + c * 16;
      *(int4v*)(dstr + (kb ^ sw)) = *(const int4v*)(src + c * 16);
    }
  }
  int lane = tid & 63, wv = tid >> 6, wr = wv >> 2, wc = wv & 3;
  int l15 = lane & 15, g = lane >> 4;
  f32x4 zro = {0.f, 0.f, 0.f, 0.f};
  f32x4 acc[4][4];
  #pragma unroll
  for (int a = 0; a < 4; ++a)
    #pragma unroll
    for (int bq = 0; bq < 4; ++bq) acc[a][bq] = zro;
  int arow = tid >> 2, aq = tid & 3;       // 4 threads/row, 16B each
  const unsigned short* Ap = Xa + (size_t)(bidx * 128 + arow) * 256;
  for (int ks = 0; ks < 8; ++ks){
    __syncthreads();
    {
      const unsigned short* s = Ap + ks * 32 + aq * 8;
      char* base = As + arow * 64;
      int kb = aq * 16, sw = (arow & 7) << 3;
      *(short4v*)(base + ((kb    ) ^ sw)) = *(const short4v*)(s);
      *(short4v*)(base + ((kb + 8) ^ sw)) = *(const short4v*)(s + 4);
    }
    __syncthreads();
    U8 af[4];
    #pragma unroll
    for (int mt = 0; mt < 4; ++mt){
      int ar = wr * 64 + mt * 16 + l15;
      const char* ab = As + ar * 64;
      int sw = (ar & 7) << 3;
      af[mt].h[0] = *(const short4v*)(ab + ((8 * g) ^ sw));
      af[mt].h[1] = *(const short4v*)(ab + ((8 * g + 32) ^ sw));
    }
    #pragma unroll
    for (int nt = 0; nt < 4; ++nt){
      int jr = wc * 64 + nt * 16 + l15;
      const char* bb = Bsm + jr * 512;
      int kb = ks * 64 + 8 * g, sw = (jr & 7) << 4;
      U8 bf;
      bf.h[0] = *(const short4v*)(bb + (kb ^ sw));
      bf.h[1] = *(const short4v*)(bb + ((kb + 32) ^ sw));
      #pragma unroll
      for (int mt = 0; mt < 4; ++mt)
        acc[mt][nt] = __builtin_amdgcn_mfma_f32_16x16x32_bf16(af[mt].v, bf.v, acc[mt][nt], 0, 0, 0);
    }
  }
  #pragma unroll
  for (int nt = 0; nt < 4; ++nt){
    int j = j0 + wc * 64 + nt * 16 + l15;
    float bs = bias[j];
    #pragma unroll
    for (int mt = 0; mt < 4; ++mt)
      #pragma unroll
      for (int r = 0; r < 4; ++r){
        int t = wr * 64 + mt * 16 + g * 4 + r;
        float v = acc[mt][nt][r] + bs;
        size_t o = ((size_t)t * 512 + bidx) * 1024 + j;
        if (WXF32) ((float*)WxT)[o] = v;
        else       ((unsigned short*)WxT)[o] = f2bf(v);
      }
  }
}

// ---------------------------------------------------------------------------
// K5 v5 (R6 revert): LSTM, group-sharded W, relaxed-atomic flag sync.
// 256 blocks x 512 thr; group of 4 blocks = 8 batches; member m owns cols [64m,64m+64).
// All atomics RELAXED + SYSTEM scope (no buffer_inv/wbl2). Ordering: __syncthreads
// drains vmcnt => h stores complete at the coherence point before the flag store.
template<bool WXF32>
__global__ __launch_bounds__(512, 2) void k_lstm5(const void* __restrict__ WxT,
        const unsigned short* __restrict__ whh_f, float* __restrict__ out,
        unsigned int* __restrict__ hbuf, int* __restrict__ flags){
  __shared__ __align__(16) char smem[8192 + 8448];
  char* HS = smem;                    // A-layout h: [row16][k256 bf16], XOR (row&7)<<3
  float* GS = (float*)(smem + 8192);  // gate stage: [batch][gate][col], stride 264/batch
  int tid = threadIdx.x, lane = tid & 63, wv = tid >> 6;
  int l15 = lane & 15, g = lane >> 4;
  int bid = blockIdx.x;
  int x = bid & 7, q = bid >> 3;          // same-XCD grouping heuristic (bid mod 8)
  int y = q >> 2, m = q & 3;
  int grp = y * 8 + x;                    // [0,64)
  int b0 = grp * 8;
  int c0 = m * 64;
  int tb = tid >> 6, tc = tid & 63;       // gate-phase (batch, col_local)

  // ---- W slice into registers: wave w owns j_local [32w, 32w+32)
  U8 breg[2][8];
  #pragma unroll
  for (int nt = 0; nt < 2; ++nt){
    int jl = wv * 32 + nt * 16 + l15;
    int jg = (jl >> 6) * 256 + c0 + (jl & 63);
    #pragma unroll
    for (int kk = 0; kk < 8; ++kk)
      breg[nt][kk].i = *(const int4v*)((const char*)whh_f + (size_t)jg * 512 + kk * 64 + g * 16);
  }
  { int4v z = {0,0,0,0}; *(int4v*)(HS + tid * 16) = z; }   // h(=0) for t=0
  float cst = 0.f;
  __syncthreads();

  // Wx for t=0
  float wx[4];
  {
    size_t ob = ((size_t)b0 + tb) * 1024 + c0 + tc;
    #pragma unroll
    for (int gate = 0; gate < 4; ++gate)
      wx[gate] = WXF32 ? ((const float*)WxT)[ob + gate * 256]
                       : bf2f(((const unsigned short*)WxT)[ob + gate * 256]);
  }

  int swA = (l15 & 7) << 3;
  const char* hsrow = HS + l15 * 512;
  int keep = g >> 1;
  #pragma unroll 1
  for (int t = 0; t < 128; ++t){
    // ---- matmul: acc[2] = h(hi/lo 16 rows) @ Wslice
    f32x4 zro = {0.f, 0.f, 0.f, 0.f};
    f32x4 acc[2] = {zro, zro};
    #pragma unroll
    for (int kk = 0; kk < 8; ++kk){
      U8 a;
      a.h[0] = *(const short4v*)(hsrow + ((kk * 64 + 8 * g) ^ swA));
      a.h[1] = *(const short4v*)(hsrow + ((kk * 64 + 32 + 8 * g) ^ swA));
      acc[0] = __builtin_amdgcn_mfma_f32_16x16x32_bf16(a.v, breg[0][kk].v, acc[0], 0, 0, 0);
      acc[1] = __builtin_amdgcn_mfma_f32_16x16x32_bf16(a.v, breg[1][kk].v, acc[1], 0, 0, 0);
    }
    // ---- fold hi+lo (keep own nt, send the other; partner g^2 holds the other rows)
    #pragma unroll
    for (int r = 0; r < 4; ++r){
      float v0 = acc[0][r], v1 = acc[1][r];
      float kv = keep ? v1 : v0;
      float sv = keep ? v0 : v1;
      float val = kv + __shfl_xor(sv, 32);
      int jl = wv * 32 + keep * 16 + l15;
      int batch = (g & 1) * 4 + r;
      GS[batch * 264 + (jl >> 6) * 66 + (jl & 63)] = val;   // conflict-free layout
    }
    __syncthreads();
    // ---- gate phase: thread owns (tb, tc); 4 conflict-free b32 reads
    float gv0 = GS[tb * 264 +   0 + tc];
    float gv1 = GS[tb * 264 +  66 + tc];
    float gv2 = GS[tb * 264 + 132 + tc];
    float gv3 = GS[tb * 264 + 198 + tc];
    // prefetch Wx(t+1) — latency hides under publish/poll
    float wxn[4] = {0.f, 0.f, 0.f, 0.f};
    if (t < 127){
      size_t ob = ((size_t)(t + 1) * 512 + b0 + tb) * 1024 + c0 + tc;
      #pragma unroll
      for (int gate = 0; gate < 4; ++gate)
        wxn[gate] = WXF32 ? ((const float*)WxT)[ob + gate * 256]
                          : bf2f(((const unsigned short*)WxT)[ob + gate * 256]);
    }
    float gi = sigm(gv0 + wx[0]);
    float gf = sigm(gv1 + wx[1]);
    float gg = tanhf_(gv2 + wx[2]);
    float go = sigm(gv3 + wx[3]);
    float c = gf * cst + gi * gg;
    cst = c;
    float h = go * tanhf_(c);
    out[((size_t)(b0 + tb) * 128 + t) * 256 + c0 + tc] = h;
    if (t < 127){
      unsigned short hhi = f2bf(h);
      unsigned short hlo = f2bf(h - bf2f(hhi));
      unsigned int pk = (unsigned int)hhi | ((unsigned int)hlo << 16);
      unsigned int* hb = hbuf + ((size_t)grp * 2 + (t & 1)) * 2048;
      __hip_atomic_store(hb + tb * 256 + c0 + tc, pk, __ATOMIC_RELAXED, __HIP_MEMORY_SCOPE_SYSTEM);
      __syncthreads();                    // vmcnt(0) drain: h stores complete at coherence pt
      if (wv == 0){
        if (lane == 0)
          __hip_atomic_store(&flags[grp * 4 + m], t + 1, __ATOMIC_RELAXED, __HIP_MEMORY_SCOPE_SYSTEM);
        if (lane >= 1 && lane <= 3){
          int pl = lane - 1;
          int pslot = pl + (pl >= m ? 1 : 0);
          while (__hip_atomic_load(&flags[grp * 4 + pslot], __ATOMIC_RELAXED,
                                   __HIP_MEMORY_SCOPE_SYSTEM) <= t){}
        }
      }
      __syncthreads();
      // ---- reload all 256 cols of h into HS (relaxed system atomic u64 loads)
      {
        int bb = tid >> 6, cg = tid & 63;          // 4 cols per thread
        const unsigned long long* sp =
            (const unsigned long long*)(hb + bb * 256 + cg * 4);
        unsigned long long w0 = __hip_atomic_load(sp,     __ATOMIC_RELAXED, __HIP_MEMORY_SCOPE_SYSTEM);
        unsigned long long w1 = __hip_atomic_load(sp + 1, __ATOMIC_RELAXED, __HIP_MEMORY_SCOPE_SYSTEM);
        unsigned int u0 = (unsigned int)w0, u1 = (unsigned int)(w0 >> 32);
        unsigned int u2 = (unsigned int)w1, u3 = (unsigned int)(w1 >> 32);
        short4v hiv = { (short)(u0 & 0xffff), (short)(u1 & 0xffff),
                        (short)(u2 & 0xffff), (short)(u3 & 0xffff) };
        short4v lov = { (short)(u0 >> 16), (short)(u1 >> 16),
                        (short)(u2 >> 16), (short)(u3 >> 16) };
        int sw = (bb & 7) << 3;
        int cb = (cg * 8) ^ sw;
        *(short4v*)(HS + bb * 512 + cb) = hiv;
        *(short4v*)(HS + (bb + 8) * 512 + cb) = lov;
      }
      __syncthreads();
      wx[0] = wxn[0]; wx[1] = wxn[1]; wx[2] = wxn[2]; wx[3] = wxn[3];
    }
  }
}

// ---------------------------------------------------------------------------
extern "C" void kernel_launch(void* const* d_in, const int* in_sizes, int n_in,
                              void* d_out, int out_size, void* d_ws, size_t ws_size,
                              hipStream_t stream){
  (void)in_sizes; (void)n_in; (void)out_size;
  const float* X   = (const float*)d_in[0];
  const float* Wq  = (const float*)d_in[1];
  const float* Wk  = (const float*)d_in[2];
  const float* Wv  = (const float*)d_in[3];
  const float* Wih = (const float*)d_in[4];
  const float* Whh = (const float*)d_in[5];
  const float* bih = (const float*)d_in[6];
  const float* bhh = (const float*)d_in[7];
  float* out = (float*)d_out;
  char* ws = (char*)d_ws;

  const size_t SZ  = 33554432ULL;        // one (B,N,T) bf16 buffer
  const size_t WXF = 268435456ULL;       // Wx f32 (T,B,4H)
  const size_t WTS = 2200000ULL;         // casted weights + bias + hbuf + flags
  bool wxf32 = ws_size >= WXF + SZ + WTS;
  size_t wxb = wxf32 ? WXF : WXF / 2;

  unsigned short* p_xp = (unsigned short*)ws;
  unsigned short* p_q  = (unsigned short*)(ws + SZ);
  unsigned short* p_k  = (unsigned short*)(ws + 2 * SZ);
  unsigned short* p_vt = (unsigned short*)(ws + 3 * SZ);
  void* p_wx = (void*)ws;
  char* p = ws + wxb;
  unsigned short* p_xa  = (unsigned short*)p; p += SZ;
  unsigned short* p_wqb = (unsigned short*)p; p += 32768;
  unsigned short* p_wkb = (unsigned short*)p; p += 32768;
  unsigned short* p_wvb = (unsigned short*)p; p += 32768;
  unsigned short* p_wihb= (unsigned short*)p; p += 524288;
  unsigned short* p_whhf= (unsigned short*)p; p += 524288;
  float* p_bias = (float*)p; p += 4096;
  unsigned int* p_hbuf = (unsigned int*)p; p += 1048576;
  int* p_flags = (int*)p;

  k_prep<<<1024, 256, 0, stream>>>(Wq, Wk, Wv, Wih, bih, bhh,
                                   p_wqb, p_wkb, p_wvb, p_wihb, p_bias, p_flags);
  k_prep2<<<32, 256, 0, stream>>>(Whh, p_whhf);
  k_xpose<<<dim3(4, 512), 256, 0, stream>>>(X, p_xp);
  k_qkv<<<dim3(1024, 3), 256, 0, stream>>>(p_xp, p_wqb, p_wkb, p_wvb, p_q, p_k, p_vt);
  k_attn<<<dim3(4, 512), 256, 0, stream>>>(p_q, p_k, p_vt, p_xa);
  if (wxf32){
    k_wx<true><<<dim3(512, 4), 512, 0, stream>>>(p_xa, p_wihb, p_bias, p_wx);
    k_lstm5<true><<<256, 512, 0, stream>>>(p_wx, p_whhf, out, p_hbuf, p_flags);
  } else {
    k_wx<false><<<dim3(512, 4), 512, 0, stream>>>(p_xa, p_wihb, p_bias, p_wx);
    k_lstm5<false><<<256, 512, 0, stream>>>(p_wx, p_whhf, out, p_hbuf, p_flags);
  }
}

// Round 11
// 611.112 us; speedup vs baseline: 1.2280x; 1.0254x over previous
//
#include <hip/hip_runtime.h>
#include <hip/hip_bf16.h>
#include <stdint.h>

// Encoder: X->(transpose)->QKV GEMMs -> attention(softmax) -> LSTM (Wx GEMM fused in)
// B=512 T=128 N=256 H=256, all inputs f32, output f32 (B,T,H).
// Round 11: k_wx DELETED — its GEMM is fused into the LSTM. Each LSTM block owns
// j-cols [64m,64m+64) of all gates; W_ih slice (128KB) lives in LDS (chunk-XOR,
// R3-verified scheme); Xa(t) staged per step into XS with the same swizzle as the
// h A-frags; Xa@Wih accumulates into the same acc as h@Whh (fold yields the sum).
// Saves the 268MB f32 Wx write + re-read (~90us); LSTM adds ~25us of hidden compute.

#define DI __device__ __forceinline__

typedef __attribute__((ext_vector_type(8))) short bf16x8;   // 8 bf16 = 4 VGPR (MFMA A/B frag)
typedef __attribute__((ext_vector_type(4))) short short4v;  // 8B
typedef __attribute__((ext_vector_type(4))) float f32x4;    // MFMA C/D frag
typedef __attribute__((ext_vector_type(4))) int int4v;      // 16B

union U8 { bf16x8 v; short4v h[2]; int4v i; };

DI unsigned short f2bf(float x){
  union { float f; unsigned u; } v; v.f = x;
  unsigned r = v.u + 0x7fffu + ((v.u >> 16) & 1u);
  return (unsigned short)(r >> 16);
}
DI float bf2f(unsigned short x){
  union { unsigned u; float f; } v; v.u = ((unsigned)x) << 16; return v.f;
}
DI float rcp_(float x){ return __builtin_amdgcn_rcpf(x); }
DI float sigm(float x){ return rcp_(1.0f + __expf(-x)); }
DI float tanhf_(float x){ return 1.0f - 2.0f * rcp_(1.0f + __expf(2.0f * x)); }

#define BB 512
#define TT 128
#define NN 256
#define HH 256

// ---------------------------------------------------------------------------
// K0: cast QKV weights to bf16, fuse biases, zero the per-member sync flags
__global__ void k_prep(const float* __restrict__ Wq, const float* __restrict__ Wk,
                       const float* __restrict__ Wv,
                       const float* __restrict__ bih, const float* __restrict__ bhh,
                       unsigned short* __restrict__ wqb, unsigned short* __restrict__ wkb,
                       unsigned short* __restrict__ wvb,
                       float* __restrict__ bias, int* __restrict__ flags){
  int i = blockIdx.x * 256 + threadIdx.x;
  if (i < 16384){ wqb[i] = f2bf(Wq[i]); wkb[i] = f2bf(Wk[i]); wvb[i] = f2bf(Wv[i]); }
  if (i < 1024){ bias[i] = bih[i] + bhh[i]; }
  if (i < 256){ flags[i] = 0; }
}

// K0b: 1024x256 f32 W -> fragment-major bf16: frag (j, kk, g) holds
// W[j][kk*32+4g+{0..3}] , W[j][kk*32+16+4g+{0..3}].  Byte = j*512 + kk*64 + g*16.
__global__ void k_prep2(const float* __restrict__ W, unsigned short* __restrict__ w_f){
  int idx = blockIdx.x * 256 + threadIdx.x;   // 8192 = 1024 j x 8 kk
  int j = idx >> 3, kk = idx & 7;
  const float* src = W + j * 256 + kk * 32;
  unsigned short o[32];
  #pragma unroll
  for (int g = 0; g < 4; ++g)
    #pragma unroll
    for (int e = 0; e < 4; ++e){
      o[g * 8 + e]     = f2bf(src[4 * g + e]);
      o[g * 8 + 4 + e] = f2bf(src[16 + 4 * g + e]);
    }
  int4v* dst = (int4v*)((char*)w_f + j * 512 + kk * 64);
  #pragma unroll
  for (int q = 0; q < 4; ++q) dst[q] = *(int4v*)(o + q * 8);
}

// ---------------------------------------------------------------------------
// K1: X (B,T,N) f32 -> Xp (B,N,T) bf16   (tile transpose through LDS)
__global__ __launch_bounds__(256) void k_xpose(const float* __restrict__ X,
                                               unsigned short* __restrict__ Xp){
  __shared__ float tile[128][65];
  int b = blockIdx.y, n0 = blockIdx.x * 64;
  int tid = threadIdx.x;
  int nloc = tid & 63, t0 = tid >> 6;
  const float* src = X + (size_t)b * TT * NN + n0 + nloc;
  #pragma unroll
  for (int r = 0; r < 32; ++r){
    int t = r * 4 + t0;
    tile[t][nloc] = src[(size_t)t * NN];
  }
  __syncthreads();
  int tl = tid & 127, nr0 = tid >> 7;
  unsigned short* dst = Xp + ((size_t)b * NN + n0) * TT + tl;
  #pragma unroll
  for (int r = 0; r < 32; ++r){
    int n = r * 2 + nr0;
    dst[(size_t)n * TT] = f2bf(tile[tl][n]);
  }
}

// ---------------------------------------------------------------------------
// K2: Q/K/V = Xp @ W^T per batch.  M=131072 rows, N=128, K=128.  blockIdx.y = mode.
__global__ __launch_bounds__(256) void k_qkv(const unsigned short* __restrict__ Xp,
      const unsigned short* __restrict__ Wqb, const unsigned short* __restrict__ Wkb,
      const unsigned short* __restrict__ Wvb,
      unsigned short* __restrict__ Qo, unsigned short* __restrict__ Ko,
      unsigned short* __restrict__ Vo){
  __shared__ __align__(16) char smem[32768 + 8192];
  unsigned short* Bs = (unsigned short*)smem;
  char* As = smem + 32768;
  char* Os = smem;
  int mode = blockIdx.y;
  const unsigned short* W = (mode == 0) ? Wqb : ((mode == 1) ? Wkb : Wvb);
  int m0 = blockIdx.x * 128;
  int tid = threadIdx.x;

  #pragma unroll
  for (int it = 0; it < 16; ++it){
    int c = it * 256 + tid;
    int j = c >> 5;
    int kc = (c & 31) << 2;
    short4v v = *(const short4v*)(W + j * 128 + kc);
    *(short4v*)((char*)Bs + j * 256 + ((kc * 2) ^ ((j & 7) << 4))) = v;
  }

  int lane = tid & 63, wv = tid >> 6;
  int wr = wv >> 1, wc = wv & 1;
  int l15 = lane & 15, g = lane >> 4;
  f32x4 zro = {0.f, 0.f, 0.f, 0.f};
  f32x4 acc[4][4];
  #pragma unroll
  for (int a = 0; a < 4; ++a)
    #pragma unroll
    for (int bq = 0; bq < 4; ++bq) acc[a][bq] = zro;

  int arow = tid >> 1, ahalf = (tid & 1) * 16;
  const unsigned short* Ap = Xp + (size_t)(m0 + arow) * 128;

  for (int ks = 0; ks < 4; ++ks){
    __syncthreads();
    {
      const unsigned short* s = Ap + ks * 32 + ahalf;
      char* base = As + arow * 64;
      int kb = ahalf * 2;
      int sw = (arow & 7) << 3;
      *(short4v*)(base + ((kb     ) ^ sw)) = *(const short4v*)(s);
      *(short4v*)(base + ((kb +  8) ^ sw)) = *(const short4v*)(s + 4);
      *(short4v*)(base + ((kb + 16) ^ sw)) = *(const short4v*)(s + 8);
      *(short4v*)(base + ((kb + 24) ^ sw)) = *(const short4v*)(s + 12);
    }
    __syncthreads();
    U8 af[4];
    #pragma unroll
    for (int mt = 0; mt < 4; ++mt){
      int ar = wr * 64 + mt * 16 + l15;
      const char* ab = As + ar * 64;
      int sw = (ar & 7) << 3;
      af[mt].h[0] = *(const short4v*)(ab + ((8 * g) ^ sw));
      af[mt].h[1] = *(const short4v*)(ab + ((8 * g + 32) ^ sw));
    }
    #pragma unroll
    for (int nt = 0; nt < 4; ++nt){
      int jr = wc * 64 + nt * 16 + l15;
      const char* bb = (const char*)Bs + jr * 256;
      int kb = ks * 64 + 8 * g, sw = (jr & 7) << 4;
      U8 bf;
      bf.h[0] = *(const short4v*)(bb + (kb ^ sw));
      bf.h[1] = *(const short4v*)(bb + ((kb + 32) ^ sw));
      #pragma unroll
      for (int mt = 0; mt < 4; ++mt)
        acc[mt][nt] = __builtin_amdgcn_mfma_f32_16x16x32_bf16(af[mt].v, bf.v, acc[mt][nt], 0, 0, 0);
    }
  }
  __syncthreads();
  float scale = (mode == 0) ? 0.0625f : 1.0f;
  #pragma unroll
  for (int mt = 0; mt < 4; ++mt)
    #pragma unroll
    for (int nt = 0; nt < 4; ++nt)
      #pragma unroll
      for (int r = 0; r < 4; ++r){
        int row = wr * 64 + mt * 16 + g * 4 + r;
        int col = wc * 64 + nt * 16 + l15;
        unsigned short hv = f2bf(acc[mt][nt][r] * scale);
        int addr = (mode == 2) ? (col * 256 + ((row * 2) ^ ((col & 7) << 4)))
                               : (row * 256 + ((col * 2) ^ ((row & 7) << 4)));
        *(unsigned short*)(Os + addr) = hv;
      }
  __syncthreads();
  int orow = tid >> 1, oseg = tid & 1;
  const char* srcrow = Os + orow * 256;
  unsigned short* dst;
  if (mode == 2){
    int bq = m0 >> 8, ibase = m0 & 255;
    dst = Vo + ((size_t)bq * 128 + orow) * 256 + ibase + oseg * 64;
  } else {
    dst = ((mode == 0) ? Qo : Ko) + (size_t)(m0 + orow) * 128 + oseg * 64;
  }
  #pragma unroll
  for (int c = 0; c < 8; ++c){
    int kb = oseg * 128 + c * 16;
    *(int4v*)((char*)dst + c * 16) = *(const int4v*)(srcrow + (kb ^ ((orow & 7) << 4)));
  }
}

// ---------------------------------------------------------------------------
// K3: fused attention per (b, 64-row i-tile). S=QK^T, softmax, Xa^T = V^T P^T.
__global__ __launch_bounds__(256) void k_attn(const unsigned short* __restrict__ Q,
        const unsigned short* __restrict__ K, const unsigned short* __restrict__ Vt,
        unsigned short* __restrict__ Xa){
  __shared__ __align__(16) char smem[16384 + 65536 + 32768 + 256];
  char* Qs = smem;
  char* Ks = smem + 16384;
  char* Ps = smem + 16384 + 65536;
  float* rden = (float*)(smem + 16384 + 65536 + 32768);
  int b = blockIdx.y, i0 = blockIdx.x * 64;
  int tid = threadIdx.x, lane = tid & 63, wv = tid >> 6;
  int l15 = lane & 15, g = lane >> 4;

  {
    int row = tid >> 2, q = tid & 3;
    const char* src = (const char*)(Q + ((size_t)b * 256 + i0 + row) * 128) + q * 64;
    char* dstr = Qs + row * 256;
    int sw = (row & 7) << 4;
    #pragma unroll
    for (int c = 0; c < 4; ++c){
      int kb = q * 64 + c * 16;
      *(int4v*)(dstr + (kb ^ sw)) = *(const int4v*)(src + c * 16);
    }
  }
  {
    const char* src = (const char*)(K + ((size_t)b * 256 + tid) * 128);
    char* dstr = Ks + tid * 256;
    int sw = (tid & 7) << 4;
    #pragma unroll
    for (int c = 0; c < 16; ++c)
      *(int4v*)(dstr + ((c * 16) ^ sw)) = *(const int4v*)(src + c * 16);
  }
  __syncthreads();

  f32x4 zro = {0.f, 0.f, 0.f, 0.f};
  f32x4 acc[16];
  #pragma unroll
  for (int nt = 0; nt < 16; ++nt) acc[nt] = zro;
  #pragma unroll
  for (int kk = 0; kk < 4; ++kk){
    int ar = wv * 16 + l15;
    const char* ab = Qs + ar * 256;
    int kb = kk * 64 + 8 * g, swa = (ar & 7) << 4;
    U8 a;
    a.h[0] = *(const short4v*)(ab + (kb ^ swa));
    a.h[1] = *(const short4v*)(ab + ((kb + 32) ^ swa));
    #pragma unroll
    for (int nt = 0; nt < 16; ++nt){
      int jr = nt * 16 + l15;
      const char* bb = Ks + jr * 256;
      int swb = (jr & 7) << 4;
      U8 bf;
      bf.h[0] = *(const short4v*)(bb + (kb ^ swb));
      bf.h[1] = *(const short4v*)(bb + ((kb + 32) ^ swb));
      acc[nt] = __builtin_amdgcn_mfma_f32_16x16x32_bf16(a.v, bf.v, acc[nt], 0, 0, 0);
    }
  }
  float mx[4], sm[4];
  #pragma unroll
  for (int r = 0; r < 4; ++r){
    float m = acc[0][r];
    #pragma unroll
    for (int nt = 1; nt < 16; ++nt) m = fmaxf(m, acc[nt][r]);
    #pragma unroll
    for (int s = 1; s < 16; s <<= 1) m = fmaxf(m, __shfl_xor(m, s));
    mx[r] = m;
  }
  #pragma unroll
  for (int r = 0; r < 4; ++r){
    float s = 0.f;
    #pragma unroll
    for (int nt = 0; nt < 16; ++nt){
      float p = __expf(acc[nt][r] - mx[r]);
      acc[nt][r] = p; s += p;
    }
    #pragma unroll
    for (int sd = 1; sd < 16; sd <<= 1) s += __shfl_xor(s, sd);
    sm[r] = s;
  }
  #pragma unroll
  for (int nt = 0; nt < 16; ++nt)
    #pragma unroll
    for (int r = 0; r < 4; ++r){
      int ir = wv * 16 + g * 4 + r;
      *(unsigned short*)(Ps + ir * 512 + ((nt * 16 + l15) * 2 ^ ((ir & 7) << 4))) = f2bf(acc[nt][r]);
    }
  #pragma unroll
  for (int r = 0; r < 4; ++r)
    if (l15 == r) rden[wv * 16 + g * 4 + r] = rcp_(sm[r]);
  __syncthreads();
  {
    int row = tid >> 1, half = tid & 1;
    const char* src = (const char*)(Vt + ((size_t)b * 128 + row) * 256) + half * 256;
    char* dstr = Ks + row * 512;
    int sw = (row & 7) << 4;
    #pragma unroll
    for (int c = 0; c < 16; ++c){
      int jb = half * 256 + c * 16;
      *(int4v*)(dstr + (jb ^ sw)) = *(const int4v*)(src + c * 16);
    }
  }
  __syncthreads();

  f32x4 acc2[2][4];
  #pragma unroll
  for (int mt = 0; mt < 2; ++mt)
    #pragma unroll
    for (int nt = 0; nt < 4; ++nt) acc2[mt][nt] = zro;
  #pragma unroll
  for (int kk = 0; kk < 8; ++kk){
    int kb = kk * 64 + 8 * g;
    U8 bfr[4];
    #pragma unroll
    for (int nt = 0; nt < 4; ++nt){
      int ir = nt * 16 + l15;
      const char* pb = Ps + ir * 512;
      int sw = (ir & 7) << 4;
      bfr[nt].h[0] = *(const short4v*)(pb + (kb ^ sw));
      bfr[nt].h[1] = *(const short4v*)(pb + ((kb + 32) ^ sw));
    }
    #pragma unroll
    for (int mt = 0; mt < 2; ++mt){
      int tr = wv * 32 + mt * 16 + l15;
      const char* ab = Ks + tr * 512;
      int sw = (tr & 7) << 4;
      U8 a;
      a.h[0] = *(const short4v*)(ab + (kb ^ sw));
      a.h[1] = *(const short4v*)(ab + ((kb + 32) ^ sw));
      #pragma unroll
      for (int nt = 0; nt < 4; ++nt)
        acc2[mt][nt] = __builtin_amdgcn_mfma_f32_16x16x32_bf16(a.v, bfr[nt].v, acc2[mt][nt], 0, 0, 0);
    }
  }
  #pragma unroll
  for (int nt = 0; nt < 4; ++nt){
    float rd = rden[nt * 16 + l15];
    #pragma unroll
    for (int mt = 0; mt < 2; ++mt)
      #pragma unroll
      for (int r = 0; r < 4; ++r){
        int t = wv * 32 + mt * 16 + g * 4 + r;
        int i = i0 + nt * 16 + l15;
        Xa[((size_t)b * 128 + t) * 256 + i] = f2bf(acc2[mt][nt][r] * rd);
      }
  }
}

// ---------------------------------------------------------------------------
// K5 v7: LSTM with fused Wx GEMM. 256 blocks x 512 thr; group of 4 blocks = 8
// batches; member m owns gate-cols [64m,64m+64). W_hh slice in regs (breg[2][8]);
// W_ih slice in LDS (128KB, chunk-XOR); Xa(t) staged into XS (same swizzle as h
// A-frags, rows 8-15 zero). acc accumulates Whh*h_hi/lo + Wih*x; fold sums them.
// Sync: R6 flag+drain (relaxed system atomics). hbuf/flags reset by k_prep.
__global__ __launch_bounds__(512, 2) void k_lstm7(const unsigned short* __restrict__ Xa,
        const unsigned short* __restrict__ whh_f, const unsigned short* __restrict__ wih_f,
        const float* __restrict__ bias, float* __restrict__ out,
        unsigned int* __restrict__ hbuf, int* __restrict__ flags){
  __shared__ __align__(16) char smem[131072 + 8192 + 8192 + 8448];
  char* WI = smem;                       // W_ih slice frag-major, chunk XOR (jl&7)
  char* HS = smem + 131072;              // h [16 rows][512B], 8B-chunk XOR (row&7)<<3
  char* XS = smem + 139264;              // Xa(t) [16 rows][512B], same swizzle; rows 8-15 = 0
  float* GS = (float*)(smem + 147456);   // gate stage [batch][gate][col], stride 264
  int tid = threadIdx.x, lane = tid & 63, wv = tid >> 6;
  int l15 = lane & 15, g = lane >> 4;
  int bid = blockIdx.x;
  int x = bid & 7, q = bid >> 3;             // same-XCD grouping heuristic
  int y = q >> 2, m = q & 3;
  int grp = y * 8 + x;                       // [0,64)
  int b0 = grp * 8;
  int c0 = m * 64;
  int tb = tid >> 6, tc = tid & 63;          // gate-phase (batch, col_local)

  // ---- W_hh slice into registers
  U8 breg[2][8];
  #pragma unroll
  for (int nt = 0; nt < 2; ++nt){
    int jl = wv * 32 + nt * 16 + l15;
    int jg = (jl >> 6) * 256 + c0 + (jl & 63);
    #pragma unroll
    for (int kk = 0; kk < 8; ++kk)
      breg[nt][kk].i = *(const int4v*)((const char*)whh_f + (size_t)jg * 512 + kk * 64 + g * 16);
  }
  // ---- W_ih slice into LDS (fragment-major, chunk-XOR jl&7)
  {
    int jl = tid >> 1, hq = (tid & 1) * 16;
    int jg = (jl >> 6) * 256 + c0 + (jl & 63);
    const char* src = (const char*)wih_f + (size_t)jg * 512;
    char* dst = WI + jl * 512;
    int sx = jl & 7;
    #pragma unroll
    for (int c2 = 0; c2 < 16; ++c2){
      int c = hq + c2;
      *(int4v*)(dst + ((c ^ sx) << 4)) = *(const int4v*)(src + c * 16);
    }
  }
  { int4v z = {0,0,0,0}; *(int4v*)(HS + tid * 16) = z; }               // h = 0
  if (tid < 256){ int4v z = {0,0,0,0}; *(int4v*)(XS + 4096 + tid * 16) = z; }  // XS rows 8-15
  { // XS rows 0-7 = Xa(t=0)
    short4v v = *(const short4v*)(Xa + ((size_t)(b0 + tb) * 128) * 256 + tc * 4);
    *(short4v*)(XS + tb * 512 + ((tc * 8) ^ ((tb & 7) << 3))) = v;
  }
  float bs0 = bias[      c0 + tc], bs1 = bias[256 + c0 + tc];
  float bs2 = bias[512 + c0 + tc], bs3 = bias[768 + c0 + tc];
  float cst = 0.f;
  __syncthreads();

  int swA = (l15 & 7) << 3;
  const char* hsrow = HS + l15 * 512;
  const char* xsrow = XS + l15 * 512;
  const char* wib0 = WI + (wv * 32 + l15) * 512;
  const char* wib1 = WI + (wv * 32 + 16 + l15) * 512;
  int keep = g >> 1;
  #pragma unroll 1
  for (int t = 0; t < 128; ++t){
    // ---- acc = h_hi/lo @ Whh + Xa @ Wih  (M-packed; fold sums all three)
    f32x4 zro = {0.f, 0.f, 0.f, 0.f};
    f32x4 acc[2] = {zro, zro};
    #pragma unroll
    for (int kk = 0; kk < 8; ++kk){
      U8 a, a2, w0, w1;
      a.h[0]  = *(const short4v*)(hsrow + ((kk * 64 + 8 * g) ^ swA));
      a.h[1]  = *(const short4v*)(hsrow + ((kk * 64 + 32 + 8 * g) ^ swA));
      a2.h[0] = *(const short4v*)(xsrow + ((kk * 64 + 8 * g) ^ swA));
      a2.h[1] = *(const short4v*)(xsrow + ((kk * 64 + 32 + 8 * g) ^ swA));
      int cx = ((kk * 4 + g) ^ (l15 & 7)) << 4;
      w0.i = *(const int4v*)(wib0 + cx);
      w1.i = *(const int4v*)(wib1 + cx);
      acc[0] = __builtin_amdgcn_mfma_f32_16x16x32_bf16(a.v,  breg[0][kk].v, acc[0], 0, 0, 0);
      acc[1] = __builtin_amdgcn_mfma_f32_16x16x32_bf16(a.v,  breg[1][kk].v, acc[1], 0, 0, 0);
      acc[0] = __builtin_amdgcn_mfma_f32_16x16x32_bf16(a2.v, w0.v,          acc[0], 0, 0, 0);
      acc[1] = __builtin_amdgcn_mfma_f32_16x16x32_bf16(a2.v, w1.v,          acc[1], 0, 0, 0);
    }
    // ---- fold hi+lo (keep own nt, send the other; partner g^2 holds other rows)
    #pragma unroll
    for (int r = 0; r < 4; ++r){
      float v0 = acc[0][r], v1 = acc[1][r];
      float kv = keep ? v1 : v0;
      float sv = keep ? v0 : v1;
      float val = kv + __shfl_xor(sv, 32);
      int jl = wv * 32 + keep * 16 + l15;
      int batch = (g & 1) * 4 + r;
      GS[batch * 264 + (jl >> 6) * 66 + (jl & 63)] = val;
    }
    __syncthreads();
    // ---- gate phase
    float gv0 = GS[tb * 264 +   0 + tc];
    float gv1 = GS[tb * 264 +  66 + tc];
    float gv2 = GS[tb * 264 + 132 + tc];
    float gv3 = GS[tb * 264 + 198 + tc];
    short4v xan = {0, 0, 0, 0};
    if (t < 127)   // prefetch Xa(t+1); latency hides under publish/poll
      xan = *(const short4v*)(Xa + ((size_t)(b0 + tb) * 128 + (t + 1)) * 256 + tc * 4);
    float gi = sigm(gv0 + bs0);
    float gf = sigm(gv1 + bs1);
    float gg = tanhf_(gv2 + bs2);
    float go = sigm(gv3 + bs3);
    float c = gf * cst + gi * gg;
    cst = c;
    float h = go * tanhf_(c);
    out[((size_t)(b0 + tb) * 128 + t) * 256 + c0 + tc] = h;
    if (t < 127){
      unsigned short hhi = f2bf(h);
      unsigned short hlo = f2bf(h - bf2f(hhi));
      unsigned int pk = (unsigned int)hhi | ((unsigned int)hlo << 16);
      unsigned int* hb = hbuf + ((size_t)grp * 2 + (t & 1)) * 2048;
      __hip_atomic_store(hb + tb * 256 + c0 + tc, pk, __ATOMIC_RELAXED, __HIP_MEMORY_SCOPE_SYSTEM);
      __syncthreads();                  // vmcnt drain: h stores at coherence point
      if (wv == 0){
        if (lane == 0)
          __hip_atomic_store(&flags[grp * 4 + m], t + 1, __ATOMIC_RELAXED, __HIP_MEMORY_SCOPE_SYSTEM);
        if (lane >= 1 && lane <= 3){
          int pl = lane - 1;
          int pslot = pl + (pl >= m ? 1 : 0);
          while (__hip_atomic_load(&flags[grp * 4 + pslot], __ATOMIC_RELAXED,
                                   __HIP_MEMORY_SCOPE_SYSTEM) <= t){}
        }
      }
      __syncthreads();
      // ---- reload h into HS; stage Xa(t+1) into XS (reads of XS(t) all done)
      {
        int bb = tid >> 6, cg = tid & 63;
        const unsigned long long* sp =
            (const unsigned long long*)(hb + bb * 256 + cg * 4);
        unsigned long long w0 = __hip_atomic_load(sp,     __ATOMIC_RELAXED, __HIP_MEMORY_SCOPE_SYSTEM);
        unsigned long long w1 = __hip_atomic_load(sp + 1, __ATOMIC_RELAXED, __HIP_MEMORY_SCOPE_SYSTEM);
        unsigned int u0 = (unsigned int)w0, u1 = (unsigned int)(w0 >> 32);
        unsigned int u2 = (unsigned int)w1, u3 = (unsigned int)(w1 >> 32);
        short4v hiv = { (short)(u0 & 0xffff), (short)(u1 & 0xffff),
                        (short)(u2 & 0xffff), (short)(u3 & 0xffff) };
        short4v lov = { (short)(u0 >> 16), (short)(u1 >> 16),
                        (short)(u2 >> 16), (short)(u3 >> 16) };
        int sw = (bb & 7) << 3;
        int cb = (cg * 8) ^ sw;
        *(short4v*)(HS + bb * 512 + cb) = hiv;
        *(short4v*)(HS + (bb + 8) * 512 + cb) = lov;
        *(short4v*)(XS + bb * 512 + cb) = xan;
      }
      __syncthreads();
    }
  }
}

// ---------------------------------------------------------------------------
extern "C" void kernel_launch(void* const* d_in, const int* in_sizes, int n_in,
                              void* d_out, int out_size, void* d_ws, size_t ws_size,
                              hipStream_t stream){
  (void)in_sizes; (void)n_in; (void)out_size; (void)ws_size;
  const float* X   = (const float*)d_in[0];
  const float* Wq  = (const float*)d_in[1];
  const float* Wk  = (const float*)d_in[2];
  const float* Wv  = (const float*)d_in[3];
  const float* Wih = (const float*)d_in[4];
  const float* Whh = (const float*)d_in[5];
  const float* bih = (const float*)d_in[6];
  const float* bhh = (const float*)d_in[7];
  float* out = (float*)d_out;
  char* ws = (char*)d_ws;

  const size_t SZ = 33554432ULL;         // one (B,N,T)/(B,T,N) bf16 buffer
  unsigned short* p_xp = (unsigned short*)ws;
  unsigned short* p_q  = (unsigned short*)(ws + SZ);
  unsigned short* p_k  = (unsigned short*)(ws + 2 * SZ);
  unsigned short* p_vt = (unsigned short*)(ws + 3 * SZ);
  unsigned short* p_xa = (unsigned short*)(ws + 4 * SZ);
  char* p = ws + 5 * SZ;
  unsigned short* p_wqb = (unsigned short*)p; p += 32768;
  unsigned short* p_wkb = (unsigned short*)p; p += 32768;
  unsigned short* p_wvb = (unsigned short*)p; p += 32768;
  unsigned short* p_whhf= (unsigned short*)p; p += 524288;
  unsigned short* p_wihf= (unsigned short*)p; p += 524288;
  float* p_bias = (float*)p; p += 4096;
  unsigned int* p_hbuf = (unsigned int*)p; p += 1048576;
  int* p_flags = (int*)p;

  k_prep<<<64, 256, 0, stream>>>(Wq, Wk, Wv, bih, bhh,
                                 p_wqb, p_wkb, p_wvb, p_bias, p_flags);
  k_prep2<<<32, 256, 0, stream>>>(Whh, p_whhf);
  k_prep2<<<32, 256, 0, stream>>>(Wih, p_wihf);
  k_xpose<<<dim3(4, 512), 256, 0, stream>>>(X, p_xp);
  k_qkv<<<dim3(1024, 3), 256, 0, stream>>>(p_xp, p_wqb, p_wkb, p_wvb, p_q, p_k, p_vt);
  k_attn<<<dim3(4, 512), 256, 0, stream>>>(p_q, p_k, p_vt, p_xa);
  k_lstm7<<<256, 512, 0, stream>>>(p_xa, p_whhf, p_wihf, p_bias, out, p_hbuf, p_flags);
}

// Round 12
// 528.198 us; speedup vs baseline: 1.4208x; 1.1570x over previous
//
#include <hip/hip_runtime.h>
#include <hip/hip_bf16.h>
#include <stdint.h>

// Encoder: X->(transpose)->QKV GEMMs -> attention(softmax) -> LSTM (Wx GEMM fused in)
// B=512 T=128 N=256 H=256, all inputs f32, output f32 (B,T,H).
// Round 12: k_lstm8 — Xa@Wih MFMAs moved into the poll-wait shadow. Per step the
// critical path is only h@Whh (acc initialized from accX); accX(t+1)=Xa(t+1)@Wih is
// computed by all waves between the flag store and the poll, overlapping the
// partners' publish latency. (R11 put it on the serial path: +2000 cy/step.)

#define DI __device__ __forceinline__

typedef __attribute__((ext_vector_type(8))) short bf16x8;   // 8 bf16 = 4 VGPR (MFMA A/B frag)
typedef __attribute__((ext_vector_type(4))) short short4v;  // 8B
typedef __attribute__((ext_vector_type(4))) float f32x4;    // MFMA C/D frag
typedef __attribute__((ext_vector_type(4))) int int4v;      // 16B

union U8 { bf16x8 v; short4v h[2]; int4v i; };

DI unsigned short f2bf(float x){
  union { float f; unsigned u; } v; v.f = x;
  unsigned r = v.u + 0x7fffu + ((v.u >> 16) & 1u);
  return (unsigned short)(r >> 16);
}
DI float bf2f(unsigned short x){
  union { unsigned u; float f; } v; v.u = ((unsigned)x) << 16; return v.f;
}
DI float rcp_(float x){ return __builtin_amdgcn_rcpf(x); }
DI float sigm(float x){ return rcp_(1.0f + __expf(-x)); }
DI float tanhf_(float x){ return 1.0f - 2.0f * rcp_(1.0f + __expf(2.0f * x)); }

#define BB 512
#define TT 128
#define NN 256
#define HH 256

// ---------------------------------------------------------------------------
// K0: cast QKV weights to bf16, fuse biases, zero the per-member sync flags
__global__ void k_prep(const float* __restrict__ Wq, const float* __restrict__ Wk,
                       const float* __restrict__ Wv,
                       const float* __restrict__ bih, const float* __restrict__ bhh,
                       unsigned short* __restrict__ wqb, unsigned short* __restrict__ wkb,
                       unsigned short* __restrict__ wvb,
                       float* __restrict__ bias, int* __restrict__ flags){
  int i = blockIdx.x * 256 + threadIdx.x;
  if (i < 16384){ wqb[i] = f2bf(Wq[i]); wkb[i] = f2bf(Wk[i]); wvb[i] = f2bf(Wv[i]); }
  if (i < 1024){ bias[i] = bih[i] + bhh[i]; }
  if (i < 256){ flags[i] = 0; }
}

// K0b: 1024x256 f32 W -> fragment-major bf16: frag (j, kk, g) holds
// W[j][kk*32+4g+{0..3}] , W[j][kk*32+16+4g+{0..3}].  Byte = j*512 + kk*64 + g*16.
__global__ void k_prep2(const float* __restrict__ W, unsigned short* __restrict__ w_f){
  int idx = blockIdx.x * 256 + threadIdx.x;   // 8192 = 1024 j x 8 kk
  int j = idx >> 3, kk = idx & 7;
  const float* src = W + j * 256 + kk * 32;
  unsigned short o[32];
  #pragma unroll
  for (int g = 0; g < 4; ++g)
    #pragma unroll
    for (int e = 0; e < 4; ++e){
      o[g * 8 + e]     = f2bf(src[4 * g + e]);
      o[g * 8 + 4 + e] = f2bf(src[16 + 4 * g + e]);
    }
  int4v* dst = (int4v*)((char*)w_f + j * 512 + kk * 64);
  #pragma unroll
  for (int q = 0; q < 4; ++q) dst[q] = *(int4v*)(o + q * 8);
}

// ---------------------------------------------------------------------------
// K1: X (B,T,N) f32 -> Xp (B,N,T) bf16   (tile transpose through LDS)
__global__ __launch_bounds__(256) void k_xpose(const float* __restrict__ X,
                                               unsigned short* __restrict__ Xp){
  __shared__ float tile[128][65];
  int b = blockIdx.y, n0 = blockIdx.x * 64;
  int tid = threadIdx.x;
  int nloc = tid & 63, t0 = tid >> 6;
  const float* src = X + (size_t)b * TT * NN + n0 + nloc;
  #pragma unroll
  for (int r = 0; r < 32; ++r){
    int t = r * 4 + t0;
    tile[t][nloc] = src[(size_t)t * NN];
  }
  __syncthreads();
  int tl = tid & 127, nr0 = tid >> 7;
  unsigned short* dst = Xp + ((size_t)b * NN + n0) * TT + tl;
  #pragma unroll
  for (int r = 0; r < 32; ++r){
    int n = r * 2 + nr0;
    dst[(size_t)n * TT] = f2bf(tile[tl][n]);
  }
}

// ---------------------------------------------------------------------------
// K2: Q/K/V = Xp @ W^T per batch.  M=131072 rows, N=128, K=128.  blockIdx.y = mode.
__global__ __launch_bounds__(256) void k_qkv(const unsigned short* __restrict__ Xp,
      const unsigned short* __restrict__ Wqb, const unsigned short* __restrict__ Wkb,
      const unsigned short* __restrict__ Wvb,
      unsigned short* __restrict__ Qo, unsigned short* __restrict__ Ko,
      unsigned short* __restrict__ Vo){
  __shared__ __align__(16) char smem[32768 + 8192];
  unsigned short* Bs = (unsigned short*)smem;
  char* As = smem + 32768;
  char* Os = smem;
  int mode = blockIdx.y;
  const unsigned short* W = (mode == 0) ? Wqb : ((mode == 1) ? Wkb : Wvb);
  int m0 = blockIdx.x * 128;
  int tid = threadIdx.x;

  #pragma unroll
  for (int it = 0; it < 16; ++it){
    int c = it * 256 + tid;
    int j = c >> 5;
    int kc = (c & 31) << 2;
    short4v v = *(const short4v*)(W + j * 128 + kc);
    *(short4v*)((char*)Bs + j * 256 + ((kc * 2) ^ ((j & 7) << 4))) = v;
  }

  int lane = tid & 63, wv = tid >> 6;
  int wr = wv >> 1, wc = wv & 1;
  int l15 = lane & 15, g = lane >> 4;
  f32x4 zro = {0.f, 0.f, 0.f, 0.f};
  f32x4 acc[4][4];
  #pragma unroll
  for (int a = 0; a < 4; ++a)
    #pragma unroll
    for (int bq = 0; bq < 4; ++bq) acc[a][bq] = zro;

  int arow = tid >> 1, ahalf = (tid & 1) * 16;
  const unsigned short* Ap = Xp + (size_t)(m0 + arow) * 128;

  for (int ks = 0; ks < 4; ++ks){
    __syncthreads();
    {
      const unsigned short* s = Ap + ks * 32 + ahalf;
      char* base = As + arow * 64;
      int kb = ahalf * 2;
      int sw = (arow & 7) << 3;
      *(short4v*)(base + ((kb     ) ^ sw)) = *(const short4v*)(s);
      *(short4v*)(base + ((kb +  8) ^ sw)) = *(const short4v*)(s + 4);
      *(short4v*)(base + ((kb + 16) ^ sw)) = *(const short4v*)(s + 8);
      *(short4v*)(base + ((kb + 24) ^ sw)) = *(const short4v*)(s + 12);
    }
    __syncthreads();
    U8 af[4];
    #pragma unroll
    for (int mt = 0; mt < 4; ++mt){
      int ar = wr * 64 + mt * 16 + l15;
      const char* ab = As + ar * 64;
      int sw = (ar & 7) << 3;
      af[mt].h[0] = *(const short4v*)(ab + ((8 * g) ^ sw));
      af[mt].h[1] = *(const short4v*)(ab + ((8 * g + 32) ^ sw));
    }
    #pragma unroll
    for (int nt = 0; nt < 4; ++nt){
      int jr = wc * 64 + nt * 16 + l15;
      const char* bb = (const char*)Bs + jr * 256;
      int kb = ks * 64 + 8 * g, sw = (jr & 7) << 4;
      U8 bf;
      bf.h[0] = *(const short4v*)(bb + (kb ^ sw));
      bf.h[1] = *(const short4v*)(bb + ((kb + 32) ^ sw));
      #pragma unroll
      for (int mt = 0; mt < 4; ++mt)
        acc[mt][nt] = __builtin_amdgcn_mfma_f32_16x16x32_bf16(af[mt].v, bf.v, acc[mt][nt], 0, 0, 0);
    }
  }
  __syncthreads();
  float scale = (mode == 0) ? 0.0625f : 1.0f;
  #pragma unroll
  for (int mt = 0; mt < 4; ++mt)
    #pragma unroll
    for (int nt = 0; nt < 4; ++nt)
      #pragma unroll
      for (int r = 0; r < 4; ++r){
        int row = wr * 64 + mt * 16 + g * 4 + r;
        int col = wc * 64 + nt * 16 + l15;
        unsigned short hv = f2bf(acc[mt][nt][r] * scale);
        int addr = (mode == 2) ? (col * 256 + ((row * 2) ^ ((col & 7) << 4)))
                               : (row * 256 + ((col * 2) ^ ((row & 7) << 4)));
        *(unsigned short*)(Os + addr) = hv;
      }
  __syncthreads();
  int orow = tid >> 1, oseg = tid & 1;
  const char* srcrow = Os + orow * 256;
  unsigned short* dst;
  if (mode == 2){
    int bq = m0 >> 8, ibase = m0 & 255;
    dst = Vo + ((size_t)bq * 128 + orow) * 256 + ibase + oseg * 64;
  } else {
    dst = ((mode == 0) ? Qo : Ko) + (size_t)(m0 + orow) * 128 + oseg * 64;
  }
  #pragma unroll
  for (int c = 0; c < 8; ++c){
    int kb = oseg * 128 + c * 16;
    *(int4v*)((char*)dst + c * 16) = *(const int4v*)(srcrow + (kb ^ ((orow & 7) << 4)));
  }
}

// ---------------------------------------------------------------------------
// K3: fused attention per (b, 64-row i-tile). S=QK^T, softmax, Xa^T = V^T P^T.
__global__ __launch_bounds__(256) void k_attn(const unsigned short* __restrict__ Q,
        const unsigned short* __restrict__ K, const unsigned short* __restrict__ Vt,
        unsigned short* __restrict__ Xa){
  __shared__ __align__(16) char smem[16384 + 65536 + 32768 + 256];
  char* Qs = smem;
  char* Ks = smem + 16384;
  char* Ps = smem + 16384 + 65536;
  float* rden = (float*)(smem + 16384 + 65536 + 32768);
  int b = blockIdx.y, i0 = blockIdx.x * 64;
  int tid = threadIdx.x, lane = tid & 63, wv = tid >> 6;
  int l15 = lane & 15, g = lane >> 4;

  {
    int row = tid >> 2, q = tid & 3;
    const char* src = (const char*)(Q + ((size_t)b * 256 + i0 + row) * 128) + q * 64;
    char* dstr = Qs + row * 256;
    int sw = (row & 7) << 4;
    #pragma unroll
    for (int c = 0; c < 4; ++c){
      int kb = q * 64 + c * 16;
      *(int4v*)(dstr + (kb ^ sw)) = *(const int4v*)(src + c * 16);
    }
  }
  {
    const char* src = (const char*)(K + ((size_t)b * 256 + tid) * 128);
    char* dstr = Ks + tid * 256;
    int sw = (tid & 7) << 4;
    #pragma unroll
    for (int c = 0; c < 16; ++c)
      *(int4v*)(dstr + ((c * 16) ^ sw)) = *(const int4v*)(src + c * 16);
  }
  __syncthreads();

  f32x4 zro = {0.f, 0.f, 0.f, 0.f};
  f32x4 acc[16];
  #pragma unroll
  for (int nt = 0; nt < 16; ++nt) acc[nt] = zro;
  #pragma unroll
  for (int kk = 0; kk < 4; ++kk){
    int ar = wv * 16 + l15;
    const char* ab = Qs + ar * 256;
    int kb = kk * 64 + 8 * g, swa = (ar & 7) << 4;
    U8 a;
    a.h[0] = *(const short4v*)(ab + (kb ^ swa));
    a.h[1] = *(const short4v*)(ab + ((kb + 32) ^ swa));
    #pragma unroll
    for (int nt = 0; nt < 16; ++nt){
      int jr = nt * 16 + l15;
      const char* bb = Ks + jr * 256;
      int swb = (jr & 7) << 4;
      U8 bf;
      bf.h[0] = *(const short4v*)(bb + (kb ^ swb));
      bf.h[1] = *(const short4v*)(bb + ((kb + 32) ^ swb));
      acc[nt] = __builtin_amdgcn_mfma_f32_16x16x32_bf16(a.v, bf.v, acc[nt], 0, 0, 0);
    }
  }
  float mx[4], sm[4];
  #pragma unroll
  for (int r = 0; r < 4; ++r){
    float m = acc[0][r];
    #pragma unroll
    for (int nt = 1; nt < 16; ++nt) m = fmaxf(m, acc[nt][r]);
    #pragma unroll
    for (int s = 1; s < 16; s <<= 1) m = fmaxf(m, __shfl_xor(m, s));
    mx[r] = m;
  }
  #pragma unroll
  for (int r = 0; r < 4; ++r){
    float s = 0.f;
    #pragma unroll
    for (int nt = 0; nt < 16; ++nt){
      float p = __expf(acc[nt][r] - mx[r]);
      acc[nt][r] = p; s += p;
    }
    #pragma unroll
    for (int sd = 1; sd < 16; sd <<= 1) s += __shfl_xor(s, sd);
    sm[r] = s;
  }
  #pragma unroll
  for (int nt = 0; nt < 16; ++nt)
    #pragma unroll
    for (int r = 0; r < 4; ++r){
      int ir = wv * 16 + g * 4 + r;
      *(unsigned short*)(Ps + ir * 512 + ((nt * 16 + l15) * 2 ^ ((ir & 7) << 4))) = f2bf(acc[nt][r]);
    }
  #pragma unroll
  for (int r = 0; r < 4; ++r)
    if (l15 == r) rden[wv * 16 + g * 4 + r] = rcp_(sm[r]);
  __syncthreads();
  {
    int row = tid >> 1, half = tid & 1;
    const char* src = (const char*)(Vt + ((size_t)b * 128 + row) * 256) + half * 256;
    char* dstr = Ks + row * 512;
    int sw = (row & 7) << 4;
    #pragma unroll
    for (int c = 0; c < 16; ++c){
      int jb = half * 256 + c * 16;
      *(int4v*)(dstr + (jb ^ sw)) = *(const int4v*)(src + c * 16);
    }
  }
  __syncthreads();

  f32x4 acc2[2][4];
  #pragma unroll
  for (int mt = 0; mt < 2; ++mt)
    #pragma unroll
    for (int nt = 0; nt < 4; ++nt) acc2[mt][nt] = zro;
  #pragma unroll
  for (int kk = 0; kk < 8; ++kk){
    int kb = kk * 64 + 8 * g;
    U8 bfr[4];
    #pragma unroll
    for (int nt = 0; nt < 4; ++nt){
      int ir = nt * 16 + l15;
      const char* pb = Ps + ir * 512;
      int sw = (ir & 7) << 4;
      bfr[nt].h[0] = *(const short4v*)(pb + (kb ^ sw));
      bfr[nt].h[1] = *(const short4v*)(pb + ((kb + 32) ^ sw));
    }
    #pragma unroll
    for (int mt = 0; mt < 2; ++mt){
      int tr = wv * 32 + mt * 16 + l15;
      const char* ab = Ks + tr * 512;
      int sw = (tr & 7) << 4;
      U8 a;
      a.h[0] = *(const short4v*)(ab + (kb ^ sw));
      a.h[1] = *(const short4v*)(ab + ((kb + 32) ^ sw));
      #pragma unroll
      for (int nt = 0; nt < 4; ++nt)
        acc2[mt][nt] = __builtin_amdgcn_mfma_f32_16x16x32_bf16(a.v, bfr[nt].v, acc2[mt][nt], 0, 0, 0);
    }
  }
  #pragma unroll
  for (int nt = 0; nt < 4; ++nt){
    float rd = rden[nt * 16 + l15];
    #pragma unroll
    for (int mt = 0; mt < 2; ++mt)
      #pragma unroll
      for (int r = 0; r < 4; ++r){
        int t = wv * 32 + mt * 16 + g * 4 + r;
        int i = i0 + nt * 16 + l15;
        Xa[((size_t)b * 128 + t) * 256 + i] = f2bf(acc2[mt][nt][r] * rd);
      }
  }
}

// ---------------------------------------------------------------------------
// K5 v8: LSTM with fused Wx GEMM, accX pipelined into the poll shadow.
// 256 blocks x 512 thr; group of 4 blocks = 8 batches; member m owns cols [64m,64m+64).
// Per step: acc = accX(t) + h@Whh (16 MFMA critical path); after drain+flag-store,
// ALL waves compute accX(t+1)=Xa(t+1)@Wih (hidden under partners' publish); wave0
// polls after. XS staged at gate phase from a prefetched register.
__global__ __launch_bounds__(512, 2) void k_lstm8(const unsigned short* __restrict__ Xa,
        const unsigned short* __restrict__ whh_f, const unsigned short* __restrict__ wih_f,
        const float* __restrict__ bias, float* __restrict__ out,
        unsigned int* __restrict__ hbuf, int* __restrict__ flags){
  __shared__ __align__(16) char smem[131072 + 8192 + 8192 + 8448];
  char* WI = smem;                       // W_ih slice frag-major, chunk XOR (jl&7)
  char* HS = smem + 131072;              // h [16 rows][512B], 8B-chunk XOR (row&7)<<3
  char* XS = smem + 139264;              // Xa(t) [16 rows][512B], same swizzle; rows 8-15 = 0
  float* GS = (float*)(smem + 147456);   // gate stage [batch][gate][col], stride 264
  int tid = threadIdx.x, lane = tid & 63, wv = tid >> 6;
  int l15 = lane & 15, g = lane >> 4;
  int bid = blockIdx.x;
  int x = bid & 7, q = bid >> 3;             // same-XCD grouping heuristic
  int y = q >> 2, m = q & 3;
  int grp = y * 8 + x;                       // [0,64)
  int b0 = grp * 8;
  int c0 = m * 64;
  int tb = tid >> 6, tc = tid & 63;          // gate-phase (batch, col_local)

  // ---- W_hh slice into registers
  U8 breg[2][8];
  #pragma unroll
  for (int nt = 0; nt < 2; ++nt){
    int jl = wv * 32 + nt * 16 + l15;
    int jg = (jl >> 6) * 256 + c0 + (jl & 63);
    #pragma unroll
    for (int kk = 0; kk < 8; ++kk)
      breg[nt][kk].i = *(const int4v*)((const char*)whh_f + (size_t)jg * 512 + kk * 64 + g * 16);
  }
  // ---- W_ih slice into LDS (fragment-major, chunk-XOR jl&7)
  {
    int jl = tid >> 1, hq = (tid & 1) * 16;
    int jg = (jl >> 6) * 256 + c0 + (jl & 63);
    const char* src = (const char*)wih_f + (size_t)jg * 512;
    char* dst = WI + jl * 512;
    int sx = jl & 7;
    #pragma unroll
    for (int c2 = 0; c2 < 16; ++c2){
      int c = hq + c2;
      *(int4v*)(dst + ((c ^ sx) << 4)) = *(const int4v*)(src + c * 16);
    }
  }
  { int4v z = {0,0,0,0}; *(int4v*)(HS + tid * 16) = z; }               // h = 0
  if (tid < 256){ int4v z = {0,0,0,0}; *(int4v*)(XS + 4096 + tid * 16) = z; }  // XS rows 8-15
  { // XS rows 0-7 = Xa(t=0)
    short4v v = *(const short4v*)(Xa + ((size_t)(b0 + tb) * 128) * 256 + tc * 4);
    *(short4v*)(XS + tb * 512 + ((tc * 8) ^ ((tb & 7) << 3))) = v;
  }
  float bs0 = bias[      c0 + tc], bs1 = bias[256 + c0 + tc];
  float bs2 = bias[512 + c0 + tc], bs3 = bias[768 + c0 + tc];
  float cst = 0.f;
  __syncthreads();

  int swA = (l15 & 7) << 3;
  const char* hsrow = HS + l15 * 512;
  const char* xsrow = XS + l15 * 512;
  const char* wib0 = WI + (wv * 32 + l15) * 512;
  const char* wib1 = WI + (wv * 32 + 16 + l15) * 512;
  int keep = g >> 1;
  f32x4 zro = {0.f, 0.f, 0.f, 0.f};

  // ---- accX(0) = Xa(0) @ Wih
  f32x4 accX[2] = {zro, zro};
  #pragma unroll
  for (int kk = 0; kk < 8; ++kk){
    U8 a2, w0, w1;
    a2.h[0] = *(const short4v*)(xsrow + ((kk * 64 + 8 * g) ^ swA));
    a2.h[1] = *(const short4v*)(xsrow + ((kk * 64 + 32 + 8 * g) ^ swA));
    int cx = ((kk * 4 + g) ^ (l15 & 7)) << 4;
    w0.i = *(const int4v*)(wib0 + cx);
    w1.i = *(const int4v*)(wib1 + cx);
    accX[0] = __builtin_amdgcn_mfma_f32_16x16x32_bf16(a2.v, w0.v, accX[0], 0, 0, 0);
    accX[1] = __builtin_amdgcn_mfma_f32_16x16x32_bf16(a2.v, w1.v, accX[1], 0, 0, 0);
  }

  #pragma unroll 1
  for (int t = 0; t < 128; ++t){
    // prefetch Xa(t+1) (latency hides under matmul+fold)
    short4v xan = {0, 0, 0, 0};
    if (t < 127)
      xan = *(const short4v*)(Xa + ((size_t)(b0 + tb) * 128 + (t + 1)) * 256 + tc * 4);
    // ---- critical path: acc = accX + h_hi/lo @ Whh
    f32x4 acc[2] = {accX[0], accX[1]};
    #pragma unroll
    for (int kk = 0; kk < 8; ++kk){
      U8 a;
      a.h[0] = *(const short4v*)(hsrow + ((kk * 64 + 8 * g) ^ swA));
      a.h[1] = *(const short4v*)(hsrow + ((kk * 64 + 32 + 8 * g) ^ swA));
      acc[0] = __builtin_amdgcn_mfma_f32_16x16x32_bf16(a.v, breg[0][kk].v, acc[0], 0, 0, 0);
      acc[1] = __builtin_amdgcn_mfma_f32_16x16x32_bf16(a.v, breg[1][kk].v, acc[1], 0, 0, 0);
    }
    // ---- fold hi+lo (keep own nt, send the other)
    #pragma unroll
    for (int r = 0; r < 4; ++r){
      float v0 = acc[0][r], v1 = acc[1][r];
      float kv = keep ? v1 : v0;
      float sv = keep ? v0 : v1;
      float val = kv + __shfl_xor(sv, 32);
      int jl = wv * 32 + keep * 16 + l15;
      int batch = (g & 1) * 4 + r;
      GS[batch * 264 + (jl >> 6) * 66 + (jl & 63)] = val;
    }
    __syncthreads();                       // A: fold visible; XS(t) reads all done
    // ---- gate phase
    float gv0 = GS[tb * 264 +   0 + tc];
    float gv1 = GS[tb * 264 +  66 + tc];
    float gv2 = GS[tb * 264 + 132 + tc];
    float gv3 = GS[tb * 264 + 198 + tc];
    float gi = sigm(gv0 + bs0);
    float gf = sigm(gv1 + bs1);
    float gg = tanhf_(gv2 + bs2);
    float go = sigm(gv3 + bs3);
    float c = gf * cst + gi * gg;
    cst = c;
    float h = go * tanhf_(c);
    out[((size_t)(b0 + tb) * 128 + t) * 256 + c0 + tc] = h;
    if (t < 127){
      unsigned short hhi = f2bf(h);
      unsigned short hlo = f2bf(h - bf2f(hhi));
      unsigned int pk = (unsigned int)hhi | ((unsigned int)hlo << 16);
      unsigned int* hb = hbuf + ((size_t)grp * 2 + (t & 1)) * 2048;
      __hip_atomic_store(hb + tb * 256 + c0 + tc, pk, __ATOMIC_RELAXED, __HIP_MEMORY_SCOPE_SYSTEM);
      // stage XS = Xa(t+1) (prior reads done at barrier A)
      *(short4v*)(XS + tb * 512 + ((tc * 8) ^ ((tb & 7) << 3))) = xan;
      __syncthreads();                     // B: publish drained; XS visible
      if (wv == 0 && lane == 0)
        __hip_atomic_store(&flags[grp * 4 + m], t + 1, __ATOMIC_RELAXED, __HIP_MEMORY_SCOPE_SYSTEM);
      // ---- accX(t+1) = Xa(t+1)@Wih — in the poll shadow (no h dependence)
      accX[0] = zro; accX[1] = zro;
      #pragma unroll
      for (int kk = 0; kk < 8; ++kk){
        U8 a2, w0, w1;
        a2.h[0] = *(const short4v*)(xsrow + ((kk * 64 + 8 * g) ^ swA));
        a2.h[1] = *(const short4v*)(xsrow + ((kk * 64 + 32 + 8 * g) ^ swA));
        int cx = ((kk * 4 + g) ^ (l15 & 7)) << 4;
        w0.i = *(const int4v*)(wib0 + cx);
        w1.i = *(const int4v*)(wib1 + cx);
        accX[0] = __builtin_amdgcn_mfma_f32_16x16x32_bf16(a2.v, w0.v, accX[0], 0, 0, 0);
        accX[1] = __builtin_amdgcn_mfma_f32_16x16x32_bf16(a2.v, w1.v, accX[1], 0, 0, 0);
      }
      if (wv == 0 && lane >= 1 && lane <= 3){
        int pl = lane - 1;
        int pslot = pl + (pl >= m ? 1 : 0);
        while (__hip_atomic_load(&flags[grp * 4 + pslot], __ATOMIC_RELAXED,
                                 __HIP_MEMORY_SCOPE_SYSTEM) <= t){}
      }
      __syncthreads();                     // C: partners' h visible
      // ---- reload h into HS
      {
        int bb = tid >> 6, cg = tid & 63;
        const unsigned long long* sp =
            (const unsigned long long*)(hb + bb * 256 + cg * 4);
        unsigned long long w0 = __hip_atomic_load(sp,     __ATOMIC_RELAXED, __HIP_MEMORY_SCOPE_SYSTEM);
        unsigned long long w1 = __hip_atomic_load(sp + 1, __ATOMIC_RELAXED, __HIP_MEMORY_SCOPE_SYSTEM);
        unsigned int u0 = (unsigned int)w0, u1 = (unsigned int)(w0 >> 32);
        unsigned int u2 = (unsigned int)w1, u3 = (unsigned int)(w1 >> 32);
        short4v hiv = { (short)(u0 & 0xffff), (short)(u1 & 0xffff),
                        (short)(u2 & 0xffff), (short)(u3 & 0xffff) };
        short4v lov = { (short)(u0 >> 16), (short)(u1 >> 16),
                        (short)(u2 >> 16), (short)(u3 >> 16) };
        int sw = (bb & 7) << 3;
        int cb = (cg * 8) ^ sw;
        *(short4v*)(HS + bb * 512 + cb) = hiv;
        *(short4v*)(HS + (bb + 8) * 512 + cb) = lov;
      }
      __syncthreads();                     // D: HS ready for next matmul
    }
  }
}

// ---------------------------------------------------------------------------
extern "C" void kernel_launch(void* const* d_in, const int* in_sizes, int n_in,
                              void* d_out, int out_size, void* d_ws, size_t ws_size,
                              hipStream_t stream){
  (void)in_sizes; (void)n_in; (void)out_size; (void)ws_size;
  const float* X   = (const float*)d_in[0];
  const float* Wq  = (const float*)d_in[1];
  const float* Wk  = (const float*)d_in[2];
  const float* Wv  = (const float*)d_in[3];
  const float* Wih = (const float*)d_in[4];
  const float* Whh = (const float*)d_in[5];
  const float* bih = (const float*)d_in[6];
  const float* bhh = (const float*)d_in[7];
  float* out = (float*)d_out;
  char* ws = (char*)d_ws;

  const size_t SZ = 33554432ULL;         // one (B,N,T)/(B,T,N) bf16 buffer
  unsigned short* p_xp = (unsigned short*)ws;
  unsigned short* p_q  = (unsigned short*)(ws + SZ);
  unsigned short* p_k  = (unsigned short*)(ws + 2 * SZ);
  unsigned short* p_vt = (unsigned short*)(ws + 3 * SZ);
  unsigned short* p_xa = (unsigned short*)(ws + 4 * SZ);
  char* p = ws + 5 * SZ;
  unsigned short* p_wqb = (unsigned short*)p; p += 32768;
  unsigned short* p_wkb = (unsigned short*)p; p += 32768;
  unsigned short* p_wvb = (unsigned short*)p; p += 32768;
  unsigned short* p_whhf= (unsigned short*)p; p += 524288;
  unsigned short* p_wihf= (unsigned short*)p; p += 524288;
  float* p_bias = (float*)p; p += 4096;
  unsigned int* p_hbuf = (unsigned int*)p; p += 1048576;
  int* p_flags = (int*)p;

  k_prep<<<64, 256, 0, stream>>>(Wq, Wk, Wv, bih, bhh,
                                 p_wqb, p_wkb, p_wvb, p_bias, p_flags);
  k_prep2<<<32, 256, 0, stream>>>(Whh, p_whhf);
  k_prep2<<<32, 256, 0, stream>>>(Wih, p_wihf);
  k_xpose<<<dim3(4, 512), 256, 0, stream>>>(X, p_xp);
  k_qkv<<<dim3(1024, 3), 256, 0, stream>>>(p_xp, p_wqb, p_wkb, p_wvb, p_q, p_k, p_vt);
  k_attn<<<dim3(4, 512), 256, 0, stream>>>(p_q, p_k, p_vt, p_xa);
  k_lstm8<<<256, 512, 0, stream>>>(p_xa, p_whhf, p_wihf, p_bias, out, p_hbuf, p_flags);
}

// Round 13
// 525.700 us; speedup vs baseline: 1.4275x; 1.0048x over previous
//
#include <hip/hip_runtime.h>
#include <hip/hip_bf16.h>
#include <stdint.h>

// Encoder: X -> fused(transpose+QKV GEMMs) -> attention(softmax) -> LSTM (Wx fused)
// B=512 T=128 N=256 H=256, all inputs f32, output f32 (B,T,H).
// Round 13: k_qkv2 fuses the X-transpose + all 3 QKV modes (one A-stage, 3 B-passes;
// kills k_xpose + the Xp buffer, -128MB traffic). k_attn2 widens i-tile to 128
// (K-read halved, blocks halved; LDS overlaid Qs/Ks -> Ps/Vs). k_lstm8 unchanged.

#define DI __device__ __forceinline__

typedef __attribute__((ext_vector_type(8))) short bf16x8;   // 8 bf16 = 4 VGPR (MFMA A/B frag)
typedef __attribute__((ext_vector_type(4))) short short4v;  // 8B
typedef __attribute__((ext_vector_type(4))) float f32x4;    // MFMA C/D frag
typedef __attribute__((ext_vector_type(4))) int int4v;      // 16B

union U8 { bf16x8 v; short4v h[2]; int4v i; };

DI unsigned short f2bf(float x){
  union { float f; unsigned u; } v; v.f = x;
  unsigned r = v.u + 0x7fffu + ((v.u >> 16) & 1u);
  return (unsigned short)(r >> 16);
}
DI float bf2f(unsigned short x){
  union { unsigned u; float f; } v; v.u = ((unsigned)x) << 16; return v.f;
}
DI float rcp_(float x){ return __builtin_amdgcn_rcpf(x); }
DI float sigm(float x){ return rcp_(1.0f + __expf(-x)); }
DI float tanhf_(float x){ return 1.0f - 2.0f * rcp_(1.0f + __expf(2.0f * x)); }

#define BB 512
#define TT 128
#define NN 256
#define HH 256

// ---------------------------------------------------------------------------
// K0: cast QKV weights to bf16, fuse biases, zero the per-member sync flags
__global__ void k_prep(const float* __restrict__ Wq, const float* __restrict__ Wk,
                       const float* __restrict__ Wv,
                       const float* __restrict__ bih, const float* __restrict__ bhh,
                       unsigned short* __restrict__ wqb, unsigned short* __restrict__ wkb,
                       unsigned short* __restrict__ wvb,
                       float* __restrict__ bias, int* __restrict__ flags){
  int i = blockIdx.x * 256 + threadIdx.x;
  if (i < 16384){ wqb[i] = f2bf(Wq[i]); wkb[i] = f2bf(Wk[i]); wvb[i] = f2bf(Wv[i]); }
  if (i < 1024){ bias[i] = bih[i] + bhh[i]; }
  if (i < 256){ flags[i] = 0; }
}

// K0b: 1024x256 f32 W -> fragment-major bf16: frag (j, kk, g) holds
// W[j][kk*32+4g+{0..3}] , W[j][kk*32+16+4g+{0..3}].  Byte = j*512 + kk*64 + g*16.
__global__ void k_prep2(const float* __restrict__ W, unsigned short* __restrict__ w_f){
  int idx = blockIdx.x * 256 + threadIdx.x;   // 8192 = 1024 j x 8 kk
  int j = idx >> 3, kk = idx & 7;
  const float* src = W + j * 256 + kk * 32;
  unsigned short o[32];
  #pragma unroll
  for (int g = 0; g < 4; ++g)
    #pragma unroll
    for (int e = 0; e < 4; ++e){
      o[g * 8 + e]     = f2bf(src[4 * g + e]);
      o[g * 8 + 4 + e] = f2bf(src[16 + 4 * g + e]);
    }
  int4v* dst = (int4v*)((char*)w_f + j * 512 + kk * 64);
  #pragma unroll
  for (int q = 0; q < 4; ++q) dst[q] = *(int4v*)(o + q * 8);
}

// ---------------------------------------------------------------------------
// K2 v2: fused transpose + Q/K/V. 1024 blocks x 256 thr; block = (batch, n-half).
// Phase 0: X[b][t][n0+*] f32 -> tile LDS.  Phase 1: transpose -> A bf16 (full K=128,
// 16B-XOR swizzle).  Phase 2: for mode in {Q,K,V}: stage W panel, MFMA, write out.
__global__ __launch_bounds__(256) void k_qkv2(const float* __restrict__ X,
      const unsigned short* __restrict__ Wqb, const unsigned short* __restrict__ Wkb,
      const unsigned short* __restrict__ Wvb,
      unsigned short* __restrict__ Qo, unsigned short* __restrict__ Ko,
      unsigned short* __restrict__ Vo){
  __shared__ __align__(16) char smem[98816];
  char* As2 = smem;                       // [0,32768): A bf16 [128 rows][256B], XOR (row&7)<<4
  float* tile = (float*)(smem + 32768);   // [32768,98816): f32 [128][129]
  char* Bs = smem + 32768;                // W panel (overlays tile; staged after transpose)
  char* Os = smem + 65536;                // out stage (overlays tile tail)
  int bid = blockIdx.x;
  int b = bid >> 1, nh = bid & 1;
  int n0 = nh * 128;
  int m0 = b * 256 + n0;                  // global output row base
  int tid = threadIdx.x;

  // ---- phase 0: stage X tile (coalesced along n)
  {
    int nl = tid & 127, tg = tid >> 7;
    const float* src = X + (size_t)b * TT * NN + n0 + nl;
    #pragma unroll
    for (int r = 0; r < 64; ++r){
      int t = r * 2 + tg;
      tile[t * 129 + nl] = src[(size_t)t * NN];
    }
  }
  __syncthreads();
  // ---- phase 1: transpose -> A (row = n_local, k = t)
  {
    int tpos = tid & 31, nrow = tid >> 5;    // t-chunk (4 t each), n-subrow
    #pragma unroll
    for (int rr = 0; rr < 16; ++rr){
      int n = rr * 8 + nrow;
      int t0 = tpos * 4;
      short4v v = { (short)f2bf(tile[(t0    ) * 129 + n]),
                    (short)f2bf(tile[(t0 + 1) * 129 + n]),
                    (short)f2bf(tile[(t0 + 2) * 129 + n]),
                    (short)f2bf(tile[(t0 + 3) * 129 + n]) };
      *(short4v*)(As2 + n * 256 + ((t0 * 2) ^ ((n & 7) << 4))) = v;
    }
  }

  int lane = tid & 63, wv = tid >> 6;
  int wr = wv >> 1, wc = wv & 1;
  int l15 = lane & 15, g = lane >> 4;
  f32x4 zro = {0.f, 0.f, 0.f, 0.f};

  #pragma unroll 1
  for (int mode = 0; mode < 3; ++mode){
    const unsigned short* W = (mode == 0) ? Wqb : ((mode == 1) ? Wkb : Wvb);
    __syncthreads();            // A ready / tile dead / prev Os reads done
    // ---- stage W panel (swizzle: byte = j*256 + ((k*2) ^ ((j&7)<<4)))
    #pragma unroll
    for (int it = 0; it < 16; ++it){
      int c = it * 256 + tid;
      int j = c >> 5;
      int kc = (c & 31) << 2;
      short4v v = *(const short4v*)(W + j * 128 + kc);
      *(short4v*)(Bs + j * 256 + ((kc * 2) ^ ((j & 7) << 4))) = v;
    }
    __syncthreads();
    // ---- MFMA over full K (4 windows)
    f32x4 acc[4][4];
    #pragma unroll
    for (int a = 0; a < 4; ++a)
      #pragma unroll
      for (int bq = 0; bq < 4; ++bq) acc[a][bq] = zro;
    #pragma unroll
    for (int ks = 0; ks < 4; ++ks){
      U8 af[4];
      #pragma unroll
      for (int mt = 0; mt < 4; ++mt){
        int ar = wr * 64 + mt * 16 + l15;
        const char* ab = As2 + ar * 256;
        int sw = (ar & 7) << 4;
        af[mt].h[0] = *(const short4v*)(ab + ((ks * 64 + 8 * g) ^ sw));
        af[mt].h[1] = *(const short4v*)(ab + ((ks * 64 + 8 * g + 32) ^ sw));
      }
      #pragma unroll
      for (int nt = 0; nt < 4; ++nt){
        int jr = wc * 64 + nt * 16 + l15;
        const char* bb = Bs + jr * 256;
        int kb = ks * 64 + 8 * g, sw = (jr & 7) << 4;
        U8 bf;
        bf.h[0] = *(const short4v*)(bb + (kb ^ sw));
        bf.h[1] = *(const short4v*)(bb + ((kb + 32) ^ sw));
        #pragma unroll
        for (int mt = 0; mt < 4; ++mt)
          acc[mt][nt] = __builtin_amdgcn_mfma_f32_16x16x32_bf16(af[mt].v, bf.v, acc[mt][nt], 0, 0, 0);
      }
    }
    // ---- stage to Os (V written transposed [t][i])
    float scale = (mode == 0) ? 0.0625f : 1.0f;
    #pragma unroll
    for (int mt = 0; mt < 4; ++mt)
      #pragma unroll
      for (int nt = 0; nt < 4; ++nt)
        #pragma unroll
        for (int r = 0; r < 4; ++r){
          int row = wr * 64 + mt * 16 + g * 4 + r;
          int col = wc * 64 + nt * 16 + l15;
          unsigned short hv = f2bf(acc[mt][nt][r] * scale);
          int addr = (mode == 2) ? (col * 256 + ((row * 2) ^ ((col & 7) << 4)))
                                 : (row * 256 + ((col * 2) ^ ((row & 7) << 4)));
          *(unsigned short*)(Os + addr) = hv;
        }
    __syncthreads();
    // ---- coalesced global write
    int orow = tid >> 1, oseg = tid & 1;
    const char* srcrow = Os + orow * 256;
    unsigned short* dst;
    if (mode == 2){
      dst = Vo + ((size_t)b * 128 + orow) * 256 + n0 + oseg * 64;
    } else {
      dst = ((mode == 0) ? Qo : Ko) + (size_t)(m0 + orow) * 128 + oseg * 64;
    }
    #pragma unroll
    for (int c = 0; c < 8; ++c){
      int kb = oseg * 128 + c * 16;
      *(int4v*)((char*)dst + c * 16) = *(const int4v*)(srcrow + (kb ^ ((orow & 7) << 4)));
    }
  }
}

// ---------------------------------------------------------------------------
// K3 v2: fused attention, i-tile 128. grid (2, 512), 512 thr (8 waves).
// Phase 1: Qs[0,32K) + Ks[32768,98304) -> S + softmax (regs).
// Phase 2 (overlay): Ps[0,64K) + Vs[65536,131072) -> PV -> Xa.
__global__ __launch_bounds__(512) void k_attn2(const unsigned short* __restrict__ Q,
        const unsigned short* __restrict__ K, const unsigned short* __restrict__ Vt,
        unsigned short* __restrict__ Xa){
  __shared__ __align__(16) char smem[131072 + 512];
  char* Qs = smem;                  // 128 x 256B, XOR (row&7)<<4
  char* Ks = smem + 32768;          // 256 x 256B
  char* Ps = smem;                  // 128 x 512B (phase 2)
  char* Vs = smem + 65536;          // 128 x 512B (phase 2)
  float* rden = (float*)(smem + 131072);
  int b = blockIdx.y, i0 = blockIdx.x * 128;
  int tid = threadIdx.x, lane = tid & 63, wv = tid >> 6;
  int l15 = lane & 15, g = lane >> 4;

  { // stage Q tile (128 rows x 256B)
    int row = tid >> 2, q = tid & 3;
    const char* src = (const char*)(Q + ((size_t)b * 256 + i0 + row) * 128) + q * 64;
    char* dstr = Qs + row * 256;
    int sw = (row & 7) << 4;
    #pragma unroll
    for (int c = 0; c < 4; ++c){
      int kb = q * 64 + c * 16;
      *(int4v*)(dstr + (kb ^ sw)) = *(const int4v*)(src + c * 16);
    }
  }
  { // stage K full (256 rows x 256B)
    int row = tid >> 1, half = tid & 1;
    const char* src = (const char*)(K + ((size_t)b * 256 + row) * 128) + half * 128;
    char* dstr = Ks + row * 256;
    int sw = (row & 7) << 4;
    #pragma unroll
    for (int c = 0; c < 8; ++c){
      int kb = half * 128 + c * 16;
      *(int4v*)(dstr + (kb ^ sw)) = *(const int4v*)(src + c * 16);
    }
  }
  __syncthreads();

  // ---- S = Q K^T : wave owns 16 q-rows, all 256 j
  f32x4 zro = {0.f, 0.f, 0.f, 0.f};
  f32x4 acc[16];
  #pragma unroll
  for (int nt = 0; nt < 16; ++nt) acc[nt] = zro;
  #pragma unroll
  for (int kk = 0; kk < 4; ++kk){
    int ar = wv * 16 + l15;
    const char* ab = Qs + ar * 256;
    int kb = kk * 64 + 8 * g, swa = (ar & 7) << 4;
    U8 a;
    a.h[0] = *(const short4v*)(ab + (kb ^ swa));
    a.h[1] = *(const short4v*)(ab + ((kb + 32) ^ swa));
    #pragma unroll
    for (int nt = 0; nt < 16; ++nt){
      int jr = nt * 16 + l15;
      const char* bb = Ks + jr * 256;
      int swb = (jr & 7) << 4;
      U8 bf;
      bf.h[0] = *(const short4v*)(bb + (kb ^ swb));
      bf.h[1] = *(const short4v*)(bb + ((kb + 32) ^ swb));
      acc[nt] = __builtin_amdgcn_mfma_f32_16x16x32_bf16(a.v, bf.v, acc[nt], 0, 0, 0);
    }
  }
  // ---- softmax over j (rows = wv*16 + 4g + r)
  float mx[4], sm[4];
  #pragma unroll
  for (int r = 0; r < 4; ++r){
    float m = acc[0][r];
    #pragma unroll
    for (int nt = 1; nt < 16; ++nt) m = fmaxf(m, acc[nt][r]);
    #pragma unroll
    for (int s = 1; s < 16; s <<= 1) m = fmaxf(m, __shfl_xor(m, s));
    mx[r] = m;
  }
  #pragma unroll
  for (int r = 0; r < 4; ++r){
    float s = 0.f;
    #pragma unroll
    for (int nt = 0; nt < 16; ++nt){
      float p = __expf(acc[nt][r] - mx[r]);
      acc[nt][r] = p; s += p;
    }
    #pragma unroll
    for (int sd = 1; sd < 16; sd <<= 1) s += __shfl_xor(s, sd);
    sm[r] = s;
  }
  __syncthreads();          // all S reads of Qs/Ks done -> safe to overlay Ps/Vs
  // ---- write P (bf16) + rden; stage Vs
  #pragma unroll
  for (int nt = 0; nt < 16; ++nt)
    #pragma unroll
    for (int r = 0; r < 4; ++r){
      int ir = wv * 16 + g * 4 + r;
      *(unsigned short*)(Ps + ir * 512 + ((nt * 16 + l15) * 2 ^ ((ir & 7) << 4))) = f2bf(acc[nt][r]);
    }
  #pragma unroll
  for (int r = 0; r < 4; ++r)
    if (l15 == r) rden[wv * 16 + g * 4 + r] = rcp_(sm[r]);
  { // Vs: 128 rows (t) x 512B (j)
    int row = tid >> 2, q = tid & 3;
    const char* src = (const char*)(Vt + ((size_t)b * 128 + row) * 256) + q * 128;
    char* dstr = Vs + row * 512;
    int sw = (row & 7) << 4;
    #pragma unroll
    for (int c = 0; c < 8; ++c){
      int jb = q * 128 + c * 16;
      *(int4v*)(dstr + (jb ^ sw)) = *(const int4v*)(src + c * 16);
    }
  }
  __syncthreads();

  // ---- Xa^T tile = V^T @ P^T : wave owns 16 t-rows, 128 i-cols
  f32x4 acc2[8];
  #pragma unroll
  for (int nt = 0; nt < 8; ++nt) acc2[nt] = zro;
  #pragma unroll
  for (int kk = 0; kk < 8; ++kk){
    int kb = kk * 64 + 8 * g;
    U8 bfr[8];
    #pragma unroll
    for (int nt = 0; nt < 8; ++nt){
      int ir = nt * 16 + l15;
      const char* pb = Ps + ir * 512;
      int sw = (ir & 7) << 4;
      bfr[nt].h[0] = *(const short4v*)(pb + (kb ^ sw));
      bfr[nt].h[1] = *(const short4v*)(pb + ((kb + 32) ^ sw));
    }
    int tr = wv * 16 + l15;
    const char* ab = Vs + tr * 512;
    int sw = (tr & 7) << 4;
    U8 a;
    a.h[0] = *(const short4v*)(ab + (kb ^ sw));
    a.h[1] = *(const short4v*)(ab + ((kb + 32) ^ sw));
    #pragma unroll
    for (int nt = 0; nt < 8; ++nt)
      acc2[nt] = __builtin_amdgcn_mfma_f32_16x16x32_bf16(a.v, bfr[nt].v, acc2[nt], 0, 0, 0);
  }
  #pragma unroll
  for (int nt = 0; nt < 8; ++nt){
    float rd = rden[nt * 16 + l15];
    #pragma unroll
    for (int r = 0; r < 4; ++r){
      int t = wv * 16 + g * 4 + r;
      int i = i0 + nt * 16 + l15;
      Xa[((size_t)b * 128 + t) * 256 + i] = f2bf(acc2[nt][r] * rd);
    }
  }
}

// ---------------------------------------------------------------------------
// K5 v8 (unchanged from R12): LSTM with fused Wx GEMM, accX in the poll shadow.
__global__ __launch_bounds__(512, 2) void k_lstm8(const unsigned short* __restrict__ Xa,
        const unsigned short* __restrict__ whh_f, const unsigned short* __restrict__ wih_f,
        const float* __restrict__ bias, float* __restrict__ out,
        unsigned int* __restrict__ hbuf, int* __restrict__ flags){
  __shared__ __align__(16) char smem[131072 + 8192 + 8192 + 8448];
  char* WI = smem;                       // W_ih slice frag-major, chunk XOR (jl&7)
  char* HS = smem + 131072;              // h [16 rows][512B], 8B-chunk XOR (row&7)<<3
  char* XS = smem + 139264;              // Xa(t) [16 rows][512B], same swizzle; rows 8-15 = 0
  float* GS = (float*)(smem + 147456);   // gate stage [batch][gate][col], stride 264
  int tid = threadIdx.x, lane = tid & 63, wv = tid >> 6;
  int l15 = lane & 15, g = lane >> 4;
  int bid = blockIdx.x;
  int x = bid & 7, q = bid >> 3;             // same-XCD grouping heuristic
  int y = q >> 2, m = q & 3;
  int grp = y * 8 + x;                       // [0,64)
  int b0 = grp * 8;
  int c0 = m * 64;
  int tb = tid >> 6, tc = tid & 63;          // gate-phase (batch, col_local)

  U8 breg[2][8];
  #pragma unroll
  for (int nt = 0; nt < 2; ++nt){
    int jl = wv * 32 + nt * 16 + l15;
    int jg = (jl >> 6) * 256 + c0 + (jl & 63);
    #pragma unroll
    for (int kk = 0; kk < 8; ++kk)
      breg[nt][kk].i = *(const int4v*)((const char*)whh_f + (size_t)jg * 512 + kk * 64 + g * 16);
  }
  {
    int jl = tid >> 1, hq = (tid & 1) * 16;
    int jg = (jl >> 6) * 256 + c0 + (jl & 63);
    const char* src = (const char*)wih_f + (size_t)jg * 512;
    char* dst = WI + jl * 512;
    int sx = jl & 7;
    #pragma unroll
    for (int c2 = 0; c2 < 16; ++c2){
      int c = hq + c2;
      *(int4v*)(dst + ((c ^ sx) << 4)) = *(const int4v*)(src + c * 16);
    }
  }
  { int4v z = {0,0,0,0}; *(int4v*)(HS + tid * 16) = z; }
  if (tid < 256){ int4v z = {0,0,0,0}; *(int4v*)(XS + 4096 + tid * 16) = z; }
  {
    short4v v = *(const short4v*)(Xa + ((size_t)(b0 + tb) * 128) * 256 + tc * 4);
    *(short4v*)(XS + tb * 512 + ((tc * 8) ^ ((tb & 7) << 3))) = v;
  }
  float bs0 = bias[      c0 + tc], bs1 = bias[256 + c0 + tc];
  float bs2 = bias[512 + c0 + tc], bs3 = bias[768 + c0 + tc];
  float cst = 0.f;
  __syncthreads();

  int swA = (l15 & 7) << 3;
  const char* hsrow = HS + l15 * 512;
  const char* xsrow = XS + l15 * 512;
  const char* wib0 = WI + (wv * 32 + l15) * 512;
  const char* wib1 = WI + (wv * 32 + 16 + l15) * 512;
  int keep = g >> 1;
  f32x4 zro = {0.f, 0.f, 0.f, 0.f};

  f32x4 accX[2] = {zro, zro};
  #pragma unroll
  for (int kk = 0; kk < 8; ++kk){
    U8 a2, w0, w1;
    a2.h[0] = *(const short4v*)(xsrow + ((kk * 64 + 8 * g) ^ swA));
    a2.h[1] = *(const short4v*)(xsrow + ((kk * 64 + 32 + 8 * g) ^ swA));
    int cx = ((kk * 4 + g) ^ (l15 & 7)) << 4;
    w0.i = *(const int4v*)(wib0 + cx);
    w1.i = *(const int4v*)(wib1 + cx);
    accX[0] = __builtin_amdgcn_mfma_f32_16x16x32_bf16(a2.v, w0.v, accX[0], 0, 0, 0);
    accX[1] = __builtin_amdgcn_mfma_f32_16x16x32_bf16(a2.v, w1.v, accX[1], 0, 0, 0);
  }

  #pragma unroll 1
  for (int t = 0; t < 128; ++t){
    short4v xan = {0, 0, 0, 0};
    if (t < 127)
      xan = *(const short4v*)(Xa + ((size_t)(b0 + tb) * 128 + (t + 1)) * 256 + tc * 4);
    f32x4 acc[2] = {accX[0], accX[1]};
    #pragma unroll
    for (int kk = 0; kk < 8; ++kk){
      U8 a;
      a.h[0] = *(const short4v*)(hsrow + ((kk * 64 + 8 * g) ^ swA));
      a.h[1] = *(const short4v*)(hsrow + ((kk * 64 + 32 + 8 * g) ^ swA));
      acc[0] = __builtin_amdgcn_mfma_f32_16x16x32_bf16(a.v, breg[0][kk].v, acc[0], 0, 0, 0);
      acc[1] = __builtin_amdgcn_mfma_f32_16x16x32_bf16(a.v, breg[1][kk].v, acc[1], 0, 0, 0);
    }
    #pragma unroll
    for (int r = 0; r < 4; ++r){
      float v0 = acc[0][r], v1 = acc[1][r];
      float kv = keep ? v1 : v0;
      float sv = keep ? v0 : v1;
      float val = kv + __shfl_xor(sv, 32);
      int jl = wv * 32 + keep * 16 + l15;
      int batch = (g & 1) * 4 + r;
      GS[batch * 264 + (jl >> 6) * 66 + (jl & 63)] = val;
    }
    __syncthreads();                       // A
    float gv0 = GS[tb * 264 +   0 + tc];
    float gv1 = GS[tb * 264 +  66 + tc];
    float gv2 = GS[tb * 264 + 132 + tc];
    float gv3 = GS[tb * 264 + 198 + tc];
    float gi = sigm(gv0 + bs0);
    float gf = sigm(gv1 + bs1);
    float gg = tanhf_(gv2 + bs2);
    float go = sigm(gv3 + bs3);
    float c = gf * cst + gi * gg;
    cst = c;
    float h = go * tanhf_(c);
    out[((size_t)(b0 + tb) * 128 + t) * 256 + c0 + tc] = h;
    if (t < 127){
      unsigned short hhi = f2bf(h);
      unsigned short hlo = f2bf(h - bf2f(hhi));
      unsigned int pk = (unsigned int)hhi | ((unsigned int)hlo << 16);
      unsigned int* hb = hbuf + ((size_t)grp * 2 + (t & 1)) * 2048;
      __hip_atomic_store(hb + tb * 256 + c0 + tc, pk, __ATOMIC_RELAXED, __HIP_MEMORY_SCOPE_SYSTEM);
      *(short4v*)(XS + tb * 512 + ((tc * 8) ^ ((tb & 7) << 3))) = xan;
      __syncthreads();                     // B
      if (wv == 0 && lane == 0)
        __hip_atomic_store(&flags[grp * 4 + m], t + 1, __ATOMIC_RELAXED, __HIP_MEMORY_SCOPE_SYSTEM);
      accX[0] = zro; accX[1] = zro;
      #pragma unroll
      for (int kk = 0; kk < 8; ++kk){
        U8 a2, w0, w1;
        a2.h[0] = *(const short4v*)(xsrow + ((kk * 64 + 8 * g) ^ swA));
        a2.h[1] = *(const short4v*)(xsrow + ((kk * 64 + 32 + 8 * g) ^ swA));
        int cx = ((kk * 4 + g) ^ (l15 & 7)) << 4;
        w0.i = *(const int4v*)(wib0 + cx);
        w1.i = *(const int4v*)(wib1 + cx);
        accX[0] = __builtin_amdgcn_mfma_f32_16x16x32_bf16(a2.v, w0.v, accX[0], 0, 0, 0);
        accX[1] = __builtin_amdgcn_mfma_f32_16x16x32_bf16(a2.v, w1.v, accX[1], 0, 0, 0);
      }
      if (wv == 0 && lane >= 1 && lane <= 3){
        int pl = lane - 1;
        int pslot = pl + (pl >= m ? 1 : 0);
        while (__hip_atomic_load(&flags[grp * 4 + pslot], __ATOMIC_RELAXED,
                                 __HIP_MEMORY_SCOPE_SYSTEM) <= t){}
      }
      __syncthreads();                     // C
      {
        int bb = tid >> 6, cg = tid & 63;
        const unsigned long long* sp =
            (const unsigned long long*)(hb + bb * 256 + cg * 4);
        unsigned long long w0 = __hip_atomic_load(sp,     __ATOMIC_RELAXED, __HIP_MEMORY_SCOPE_SYSTEM);
        unsigned long long w1 = __hip_atomic_load(sp + 1, __ATOMIC_RELAXED, __HIP_MEMORY_SCOPE_SYSTEM);
        unsigned int u0 = (unsigned int)w0, u1 = (unsigned int)(w0 >> 32);
        unsigned int u2 = (unsigned int)w1, u3 = (unsigned int)(w1 >> 32);
        short4v hiv = { (short)(u0 & 0xffff), (short)(u1 & 0xffff),
                        (short)(u2 & 0xffff), (short)(u3 & 0xffff) };
        short4v lov = { (short)(u0 >> 16), (short)(u1 >> 16),
                        (short)(u2 >> 16), (short)(u3 >> 16) };
        int sw = (bb & 7) << 3;
        int cb = (cg * 8) ^ sw;
        *(short4v*)(HS + bb * 512 + cb) = hiv;
        *(short4v*)(HS + (bb + 8) * 512 + cb) = lov;
      }
      __syncthreads();                     // D
    }
  }
}

// ---------------------------------------------------------------------------
extern "C" void kernel_launch(void* const* d_in, const int* in_sizes, int n_in,
                              void* d_out, int out_size, void* d_ws, size_t ws_size,
                              hipStream_t stream){
  (void)in_sizes; (void)n_in; (void)out_size; (void)ws_size;
  const float* X   = (const float*)d_in[0];
  const float* Wq  = (const float*)d_in[1];
  const float* Wk  = (const float*)d_in[2];
  const float* Wv  = (const float*)d_in[3];
  const float* Wih = (const float*)d_in[4];
  const float* Whh = (const float*)d_in[5];
  const float* bih = (const float*)d_in[6];
  const float* bhh = (const float*)d_in[7];
  float* out = (float*)d_out;
  char* ws = (char*)d_ws;

  const size_t SZ = 33554432ULL;         // one (B,*,*) bf16 buffer
  unsigned short* p_q  = (unsigned short*)ws;
  unsigned short* p_k  = (unsigned short*)(ws + SZ);
  unsigned short* p_vt = (unsigned short*)(ws + 2 * SZ);
  unsigned short* p_xa = (unsigned short*)(ws + 3 * SZ);
  char* p = ws + 4 * SZ;
  unsigned short* p_wqb = (unsigned short*)p; p += 32768;
  unsigned short* p_wkb = (unsigned short*)p; p += 32768;
  unsigned short* p_wvb = (unsigned short*)p; p += 32768;
  unsigned short* p_whhf= (unsigned short*)p; p += 524288;
  unsigned short* p_wihf= (unsigned short*)p; p += 524288;
  float* p_bias = (float*)p; p += 4096;
  unsigned int* p_hbuf = (unsigned int*)p; p += 1048576;
  int* p_flags = (int*)p;

  k_prep<<<64, 256, 0, stream>>>(Wq, Wk, Wv, bih, bhh,
                                 p_wqb, p_wkb, p_wvb, p_bias, p_flags);
  k_prep2<<<32, 256, 0, stream>>>(Whh, p_whhf);
  k_prep2<<<32, 256, 0, stream>>>(Wih, p_wihf);
  k_qkv2<<<1024, 256, 0, stream>>>(X, p_wqb, p_wkb, p_wvb, p_q, p_k, p_vt);
  k_attn2<<<dim3(2, 512), 512, 0, stream>>>(p_q, p_k, p_vt, p_xa);
  k_lstm8<<<256, 512, 0, stream>>>(p_xa, p_whhf, p_wihf, p_bias, out, p_hbuf, p_flags);
}

// Round 14
// 514.440 us; speedup vs baseline: 1.4588x; 1.0219x over previous
//
#include <hip/hip_runtime.h>
#include <hip/hip_bf16.h>
#include <stdint.h>

// Encoder: X -> fused(transpose+QKV GEMMs) -> attention(softmax) -> LSTM (Wx fused)
// B=512 T=128 N=256 H=256, all inputs f32, output f32 (B,T,H).
// Round 14: k_lstm9 — AGENT-scope atomics, per-wave polling (barrier C deleted,
// 4->3 barriers/step), preps fused into one launch. qkv2/attn2/lstm core unchanged.

#define DI __device__ __forceinline__

typedef __attribute__((ext_vector_type(8))) short bf16x8;   // 8 bf16 = 4 VGPR (MFMA A/B frag)
typedef __attribute__((ext_vector_type(4))) short short4v;  // 8B
typedef __attribute__((ext_vector_type(4))) float f32x4;    // MFMA C/D frag
typedef __attribute__((ext_vector_type(4))) int int4v;      // 16B

union U8 { bf16x8 v; short4v h[2]; int4v i; };

DI unsigned short f2bf(float x){
  union { float f; unsigned u; } v; v.f = x;
  unsigned r = v.u + 0x7fffu + ((v.u >> 16) & 1u);
  return (unsigned short)(r >> 16);
}
DI float bf2f(unsigned short x){
  union { unsigned u; float f; } v; v.u = ((unsigned)x) << 16; return v.f;
}
DI float rcp_(float x){ return __builtin_amdgcn_rcpf(x); }
DI float sigm(float x){ return rcp_(1.0f + __expf(-x)); }
DI float tanhf_(float x){ return 1.0f - 2.0f * rcp_(1.0f + __expf(2.0f * x)); }

#define BB 512
#define TT 128
#define NN 256
#define HH 256

// ---------------------------------------------------------------------------
// K0 (fused preps): bx<64: QKV weight cast + bias + flags; bx<96: W_hh frag-pack;
// else: W_ih frag-pack.  Frag (j, kk, g) holds W[j][kk*32+4g+{0..3}],
// W[j][kk*32+16+4g+{0..3}]; byte = j*512 + kk*64 + g*16.
__global__ void k_prep3(const float* __restrict__ Wq, const float* __restrict__ Wk,
                        const float* __restrict__ Wv, const float* __restrict__ Wih,
                        const float* __restrict__ Whh,
                        const float* __restrict__ bih, const float* __restrict__ bhh,
                        unsigned short* __restrict__ wqb, unsigned short* __restrict__ wkb,
                        unsigned short* __restrict__ wvb,
                        unsigned short* __restrict__ wihf, unsigned short* __restrict__ whhf,
                        float* __restrict__ bias, int* __restrict__ flags){
  int bx = blockIdx.x;
  if (bx < 64){
    int i = bx * 256 + threadIdx.x;
    wqb[i] = f2bf(Wq[i]); wkb[i] = f2bf(Wk[i]); wvb[i] = f2bf(Wv[i]);
    if (i < 1024) bias[i] = bih[i] + bhh[i];
    if (i < 256) flags[i] = 0;
    return;
  }
  const float* W = (bx < 96) ? Whh : Wih;
  unsigned short* w_f = (bx < 96) ? whhf : wihf;
  int idx = ((bx < 96) ? (bx - 64) : (bx - 96)) * 256 + threadIdx.x;  // 8192
  int j = idx >> 3, kk = idx & 7;
  const float* src = W + j * 256 + kk * 32;
  unsigned short o[32];
  #pragma unroll
  for (int g = 0; g < 4; ++g)
    #pragma unroll
    for (int e = 0; e < 4; ++e){
      o[g * 8 + e]     = f2bf(src[4 * g + e]);
      o[g * 8 + 4 + e] = f2bf(src[16 + 4 * g + e]);
    }
  int4v* dst = (int4v*)((char*)w_f + j * 512 + kk * 64);
  #pragma unroll
  for (int q = 0; q < 4; ++q) dst[q] = *(int4v*)(o + q * 8);
}

// ---------------------------------------------------------------------------
// K2 v2: fused transpose + Q/K/V. 1024 blocks x 256 thr; block = (batch, n-half).
__global__ __launch_bounds__(256) void k_qkv2(const float* __restrict__ X,
      const unsigned short* __restrict__ Wqb, const unsigned short* __restrict__ Wkb,
      const unsigned short* __restrict__ Wvb,
      unsigned short* __restrict__ Qo, unsigned short* __restrict__ Ko,
      unsigned short* __restrict__ Vo){
  __shared__ __align__(16) char smem[98816];
  char* As2 = smem;                       // A bf16 [128 rows][256B], XOR (row&7)<<4
  float* tile = (float*)(smem + 32768);   // f32 [128][129]
  char* Bs = smem + 32768;                // W panel (overlays tile)
  char* Os = smem + 65536;                // out stage
  int bid = blockIdx.x;
  int b = bid >> 1, nh = bid & 1;
  int n0 = nh * 128;
  int m0 = b * 256 + n0;
  int tid = threadIdx.x;

  {
    int nl = tid & 127, tg = tid >> 7;
    const float* src = X + (size_t)b * TT * NN + n0 + nl;
    #pragma unroll
    for (int r = 0; r < 64; ++r){
      int t = r * 2 + tg;
      tile[t * 129 + nl] = src[(size_t)t * NN];
    }
  }
  __syncthreads();
  {
    int tpos = tid & 31, nrow = tid >> 5;
    #pragma unroll
    for (int rr = 0; rr < 16; ++rr){
      int n = rr * 8 + nrow;
      int t0 = tpos * 4;
      short4v v = { (short)f2bf(tile[(t0    ) * 129 + n]),
                    (short)f2bf(tile[(t0 + 1) * 129 + n]),
                    (short)f2bf(tile[(t0 + 2) * 129 + n]),
                    (short)f2bf(tile[(t0 + 3) * 129 + n]) };
      *(short4v*)(As2 + n * 256 + ((t0 * 2) ^ ((n & 7) << 4))) = v;
    }
  }

  int lane = tid & 63, wv = tid >> 6;
  int wr = wv >> 1, wc = wv & 1;
  int l15 = lane & 15, g = lane >> 4;
  f32x4 zro = {0.f, 0.f, 0.f, 0.f};

  #pragma unroll 1
  for (int mode = 0; mode < 3; ++mode){
    const unsigned short* W = (mode == 0) ? Wqb : ((mode == 1) ? Wkb : Wvb);
    __syncthreads();
    #pragma unroll
    for (int it = 0; it < 16; ++it){
      int c = it * 256 + tid;
      int j = c >> 5;
      int kc = (c & 31) << 2;
      short4v v = *(const short4v*)(W + j * 128 + kc);
      *(short4v*)(Bs + j * 256 + ((kc * 2) ^ ((j & 7) << 4))) = v;
    }
    __syncthreads();
    f32x4 acc[4][4];
    #pragma unroll
    for (int a = 0; a < 4; ++a)
      #pragma unroll
      for (int bq = 0; bq < 4; ++bq) acc[a][bq] = zro;
    #pragma unroll
    for (int ks = 0; ks < 4; ++ks){
      U8 af[4];
      #pragma unroll
      for (int mt = 0; mt < 4; ++mt){
        int ar = wr * 64 + mt * 16 + l15;
        const char* ab = As2 + ar * 256;
        int sw = (ar & 7) << 4;
        af[mt].h[0] = *(const short4v*)(ab + ((ks * 64 + 8 * g) ^ sw));
        af[mt].h[1] = *(const short4v*)(ab + ((ks * 64 + 8 * g + 32) ^ sw));
      }
      #pragma unroll
      for (int nt = 0; nt < 4; ++nt){
        int jr = wc * 64 + nt * 16 + l15;
        const char* bb = Bs + jr * 256;
        int kb = ks * 64 + 8 * g, sw = (jr & 7) << 4;
        U8 bf;
        bf.h[0] = *(const short4v*)(bb + (kb ^ sw));
        bf.h[1] = *(const short4v*)(bb + ((kb + 32) ^ sw));
        #pragma unroll
        for (int mt = 0; mt < 4; ++mt)
          acc[mt][nt] = __builtin_amdgcn_mfma_f32_16x16x32_bf16(af[mt].v, bf.v, acc[mt][nt], 0, 0, 0);
      }
    }
    float scale = (mode == 0) ? 0.0625f : 1.0f;
    #pragma unroll
    for (int mt = 0; mt < 4; ++mt)
      #pragma unroll
      for (int nt = 0; nt < 4; ++nt)
        #pragma unroll
        for (int r = 0; r < 4; ++r){
          int row = wr * 64 + mt * 16 + g * 4 + r;
          int col = wc * 64 + nt * 16 + l15;
          unsigned short hv = f2bf(acc[mt][nt][r] * scale);
          int addr = (mode == 2) ? (col * 256 + ((row * 2) ^ ((col & 7) << 4)))
                                 : (row * 256 + ((col * 2) ^ ((row & 7) << 4)));
          *(unsigned short*)(Os + addr) = hv;
        }
    __syncthreads();
    int orow = tid >> 1, oseg = tid & 1;
    const char* srcrow = Os + orow * 256;
    unsigned short* dst;
    if (mode == 2){
      dst = Vo + ((size_t)b * 128 + orow) * 256 + n0 + oseg * 64;
    } else {
      dst = ((mode == 0) ? Qo : Ko) + (size_t)(m0 + orow) * 128 + oseg * 64;
    }
    #pragma unroll
    for (int c = 0; c < 8; ++c){
      int kb = oseg * 128 + c * 16;
      *(int4v*)((char*)dst + c * 16) = *(const int4v*)(srcrow + (kb ^ ((orow & 7) << 4)));
    }
  }
}

// ---------------------------------------------------------------------------
// K3 v2: fused attention, i-tile 128. grid (2, 512), 512 thr (8 waves).
__global__ __launch_bounds__(512) void k_attn2(const unsigned short* __restrict__ Q,
        const unsigned short* __restrict__ K, const unsigned short* __restrict__ Vt,
        unsigned short* __restrict__ Xa){
  __shared__ __align__(16) char smem[131072 + 512];
  char* Qs = smem;                  // 128 x 256B, XOR (row&7)<<4
  char* Ks = smem + 32768;          // 256 x 256B
  char* Ps = smem;                  // 128 x 512B (phase 2)
  char* Vs = smem + 65536;          // 128 x 512B (phase 2)
  float* rden = (float*)(smem + 131072);
  int b = blockIdx.y, i0 = blockIdx.x * 128;
  int tid = threadIdx.x, lane = tid & 63, wv = tid >> 6;
  int l15 = lane & 15, g = lane >> 4;

  {
    int row = tid >> 2, q = tid & 3;
    const char* src = (const char*)(Q + ((size_t)b * 256 + i0 + row) * 128) + q * 64;
    char* dstr = Qs + row * 256;
    int sw = (row & 7) << 4;
    #pragma unroll
    for (int c = 0; c < 4; ++c){
      int kb = q * 64 + c * 16;
      *(int4v*)(dstr + (kb ^ sw)) = *(const int4v*)(src + c * 16);
    }
  }
  {
    int row = tid >> 1, half = tid & 1;
    const char* src = (const char*)(K + ((size_t)b * 256 + row) * 128) + half * 128;
    char* dstr = Ks + row * 256;
    int sw = (row & 7) << 4;
    #pragma unroll
    for (int c = 0; c < 8; ++c){
      int kb = half * 128 + c * 16;
      *(int4v*)(dstr + (kb ^ sw)) = *(const int4v*)(src + c * 16);
    }
  }
  __syncthreads();

  f32x4 zro = {0.f, 0.f, 0.f, 0.f};
  f32x4 acc[16];
  #pragma unroll
  for (int nt = 0; nt < 16; ++nt) acc[nt] = zro;
  #pragma unroll
  for (int kk = 0; kk < 4; ++kk){
    int ar = wv * 16 + l15;
    const char* ab = Qs + ar * 256;
    int kb = kk * 64 + 8 * g, swa = (ar & 7) << 4;
    U8 a;
    a.h[0] = *(const short4v*)(ab + (kb ^ swa));
    a.h[1] = *(const short4v*)(ab + ((kb + 32) ^ swa));
    #pragma unroll
    for (int nt = 0; nt < 16; ++nt){
      int jr = nt * 16 + l15;
      const char* bb = Ks + jr * 256;
      int swb = (jr & 7) << 4;
      U8 bf;
      bf.h[0] = *(const short4v*)(bb + (kb ^ swb));
      bf.h[1] = *(const short4v*)(bb + ((kb + 32) ^ swb));
      acc[nt] = __builtin_amdgcn_mfma_f32_16x16x32_bf16(a.v, bf.v, acc[nt], 0, 0, 0);
    }
  }
  float mx[4], sm[4];
  #pragma unroll
  for (int r = 0; r < 4; ++r){
    float m = acc[0][r];
    #pragma unroll
    for (int nt = 1; nt < 16; ++nt) m = fmaxf(m, acc[nt][r]);
    #pragma unroll
    for (int s = 1; s < 16; s <<= 1) m = fmaxf(m, __shfl_xor(m, s));
    mx[r] = m;
  }
  #pragma unroll
  for (int r = 0; r < 4; ++r){
    float s = 0.f;
    #pragma unroll
    for (int nt = 0; nt < 16; ++nt){
      float p = __expf(acc[nt][r] - mx[r]);
      acc[nt][r] = p; s += p;
    }
    #pragma unroll
    for (int sd = 1; sd < 16; sd <<= 1) s += __shfl_xor(s, sd);
    sm[r] = s;
  }
  __syncthreads();          // all S reads of Qs/Ks done -> safe to overlay Ps/Vs
  #pragma unroll
  for (int nt = 0; nt < 16; ++nt)
    #pragma unroll
    for (int r = 0; r < 4; ++r){
      int ir = wv * 16 + g * 4 + r;
      *(unsigned short*)(Ps + ir * 512 + ((nt * 16 + l15) * 2 ^ ((ir & 7) << 4))) = f2bf(acc[nt][r]);
    }
  #pragma unroll
  for (int r = 0; r < 4; ++r)
    if (l15 == r) rden[wv * 16 + g * 4 + r] = rcp_(sm[r]);
  {
    int row = tid >> 2, q = tid & 3;
    const char* src = (const char*)(Vt + ((size_t)b * 128 + row) * 256) + q * 128;
    char* dstr = Vs + row * 512;
    int sw = (row & 7) << 4;
    #pragma unroll
    for (int c = 0; c < 8; ++c){
      int jb = q * 128 + c * 16;
      *(int4v*)(dstr + (jb ^ sw)) = *(const int4v*)(src + c * 16);
    }
  }
  __syncthreads();

  f32x4 acc2[8];
  #pragma unroll
  for (int nt = 0; nt < 8; ++nt) acc2[nt] = zro;
  #pragma unroll
  for (int kk = 0; kk < 8; ++kk){
    int kb = kk * 64 + 8 * g;
    U8 bfr[8];
    #pragma unroll
    for (int nt = 0; nt < 8; ++nt){
      int ir = nt * 16 + l15;
      const char* pb = Ps + ir * 512;
      int sw = (ir & 7) << 4;
      bfr[nt].h[0] = *(const short4v*)(pb + (kb ^ sw));
      bfr[nt].h[1] = *(const short4v*)(pb + ((kb + 32) ^ sw));
    }
    int tr = wv * 16 + l15;
    const char* ab = Vs + tr * 512;
    int sw = (tr & 7) << 4;
    U8 a;
    a.h[0] = *(const short4v*)(ab + (kb ^ sw));
    a.h[1] = *(const short4v*)(ab + ((kb + 32) ^ sw));
    #pragma unroll
    for (int nt = 0; nt < 8; ++nt)
      acc2[nt] = __builtin_amdgcn_mfma_f32_16x16x32_bf16(a.v, bfr[nt].v, acc2[nt], 0, 0, 0);
  }
  #pragma unroll
  for (int nt = 0; nt < 8; ++nt){
    float rd = rden[nt * 16 + l15];
    #pragma unroll
    for (int r = 0; r < 4; ++r){
      int t = wv * 16 + g * 4 + r;
      int i = i0 + nt * 16 + l15;
      Xa[((size_t)b * 128 + t) * 256 + i] = f2bf(acc2[nt][r] * rd);
    }
  }
}

// ---------------------------------------------------------------------------
// K5 v9: LSTM (fused Wx), AGENT-scope atomics, per-wave polling (3 barriers/step).
// 256 blocks x 512 thr; group of 4 = 8 batches; member m owns cols [64m,64m+64).
__global__ __launch_bounds__(512, 2) void k_lstm9(const unsigned short* __restrict__ Xa,
        const unsigned short* __restrict__ whh_f, const unsigned short* __restrict__ wih_f,
        const float* __restrict__ bias, float* __restrict__ out,
        unsigned int* __restrict__ hbuf, int* __restrict__ flags){
  __shared__ __align__(16) char smem[131072 + 8192 + 8192 + 8448];
  char* WI = smem;                       // W_ih slice frag-major, chunk XOR (jl&7)
  char* HS = smem + 131072;              // h [16 rows][512B], 8B-chunk XOR (row&7)<<3
  char* XS = smem + 139264;              // Xa(t) [16 rows][512B]; rows 8-15 = 0
  float* GS = (float*)(smem + 147456);   // gate stage [batch][gate][col], stride 264
  int tid = threadIdx.x, lane = tid & 63, wv = tid >> 6;
  int l15 = lane & 15, g = lane >> 4;
  int bid = blockIdx.x;
  int x = bid & 7, q = bid >> 3;             // same-XCD grouping heuristic
  int y = q >> 2, m = q & 3;
  int grp = y * 8 + x;                       // [0,64)
  int b0 = grp * 8;
  int c0 = m * 64;
  int tb = tid >> 6, tc = tid & 63;          // gate-phase (batch, col_local)

  U8 breg[2][8];
  #pragma unroll
  for (int nt = 0; nt < 2; ++nt){
    int jl = wv * 32 + nt * 16 + l15;
    int jg = (jl >> 6) * 256 + c0 + (jl & 63);
    #pragma unroll
    for (int kk = 0; kk < 8; ++kk)
      breg[nt][kk].i = *(const int4v*)((const char*)whh_f + (size_t)jg * 512 + kk * 64 + g * 16);
  }
  {
    int jl = tid >> 1, hq = (tid & 1) * 16;
    int jg = (jl >> 6) * 256 + c0 + (jl & 63);
    const char* src = (const char*)wih_f + (size_t)jg * 512;
    char* dst = WI + jl * 512;
    int sx = jl & 7;
    #pragma unroll
    for (int c2 = 0; c2 < 16; ++c2){
      int c = hq + c2;
      *(int4v*)(dst + ((c ^ sx) << 4)) = *(const int4v*)(src + c * 16);
    }
  }
  { int4v z = {0,0,0,0}; *(int4v*)(HS + tid * 16) = z; }
  if (tid < 256){ int4v z = {0,0,0,0}; *(int4v*)(XS + 4096 + tid * 16) = z; }
  {
    short4v v = *(const short4v*)(Xa + ((size_t)(b0 + tb) * 128) * 256 + tc * 4);
    *(short4v*)(XS + tb * 512 + ((tc * 8) ^ ((tb & 7) << 3))) = v;
  }
  float bs0 = bias[      c0 + tc], bs1 = bias[256 + c0 + tc];
  float bs2 = bias[512 + c0 + tc], bs3 = bias[768 + c0 + tc];
  float cst = 0.f;
  __syncthreads();

  int swA = (l15 & 7) << 3;
  const char* hsrow = HS + l15 * 512;
  const char* xsrow = XS + l15 * 512;
  const char* wib0 = WI + (wv * 32 + l15) * 512;
  const char* wib1 = WI + (wv * 32 + 16 + l15) * 512;
  int keep = g >> 1;
  f32x4 zro = {0.f, 0.f, 0.f, 0.f};

  f32x4 accX[2] = {zro, zro};
  #pragma unroll
  for (int kk = 0; kk < 8; ++kk){
    U8 a2, w0, w1;
    a2.h[0] = *(const short4v*)(xsrow + ((kk * 64 + 8 * g) ^ swA));
    a2.h[1] = *(const short4v*)(xsrow + ((kk * 64 + 32 + 8 * g) ^ swA));
    int cx = ((kk * 4 + g) ^ (l15 & 7)) << 4;
    w0.i = *(const int4v*)(wib0 + cx);
    w1.i = *(const int4v*)(wib1 + cx);
    accX[0] = __builtin_amdgcn_mfma_f32_16x16x32_bf16(a2.v, w0.v, accX[0], 0, 0, 0);
    accX[1] = __builtin_amdgcn_mfma_f32_16x16x32_bf16(a2.v, w1.v, accX[1], 0, 0, 0);
  }

  #pragma unroll 1
  for (int t = 0; t < 128; ++t){
    short4v xan = {0, 0, 0, 0};
    if (t < 127)
      xan = *(const short4v*)(Xa + ((size_t)(b0 + tb) * 128 + (t + 1)) * 256 + tc * 4);
    f32x4 acc[2] = {accX[0], accX[1]};
    #pragma unroll
    for (int kk = 0; kk < 8; ++kk){
      U8 a;
      a.h[0] = *(const short4v*)(hsrow + ((kk * 64 + 8 * g) ^ swA));
      a.h[1] = *(const short4v*)(hsrow + ((kk * 64 + 32 + 8 * g) ^ swA));
      acc[0] = __builtin_amdgcn_mfma_f32_16x16x32_bf16(a.v, breg[0][kk].v, acc[0], 0, 0, 0);
      acc[1] = __builtin_amdgcn_mfma_f32_16x16x32_bf16(a.v, breg[1][kk].v, acc[1], 0, 0, 0);
    }
    #pragma unroll
    for (int r = 0; r < 4; ++r){
      float v0 = acc[0][r], v1 = acc[1][r];
      float kv = keep ? v1 : v0;
      float sv = keep ? v0 : v1;
      float val = kv + __shfl_xor(sv, 32);
      int jl = wv * 32 + keep * 16 + l15;
      int batch = (g & 1) * 4 + r;
      GS[batch * 264 + (jl >> 6) * 66 + (jl & 63)] = val;
    }
    __syncthreads();                       // A: fold visible; XS(t) reads done
    float gv0 = GS[tb * 264 +   0 + tc];
    float gv1 = GS[tb * 264 +  66 + tc];
    float gv2 = GS[tb * 264 + 132 + tc];
    float gv3 = GS[tb * 264 + 198 + tc];
    float gi = sigm(gv0 + bs0);
    float gf = sigm(gv1 + bs1);
    float gg = tanhf_(gv2 + bs2);
    float go = sigm(gv3 + bs3);
    float c = gf * cst + gi * gg;
    cst = c;
    float h = go * tanhf_(c);
    out[((size_t)(b0 + tb) * 128 + t) * 256 + c0 + tc] = h;
    if (t < 127){
      unsigned short hhi = f2bf(h);
      unsigned short hlo = f2bf(h - bf2f(hhi));
      unsigned int pk = (unsigned int)hhi | ((unsigned int)hlo << 16);
      unsigned int* hb = hbuf + ((size_t)grp * 2 + (t & 1)) * 2048;
      __hip_atomic_store(hb + tb * 256 + c0 + tc, pk, __ATOMIC_RELAXED, __HIP_MEMORY_SCOPE_AGENT);
      *(short4v*)(XS + tb * 512 + ((tc * 8) ^ ((tb & 7) << 3))) = xan;
      __syncthreads();                     // B: publish drained; XS visible
      if (tid == 0)
        __hip_atomic_store(&flags[grp * 4 + m], t + 1, __ATOMIC_RELAXED, __HIP_MEMORY_SCOPE_AGENT);
      // ---- accX(t+1) in the poll shadow (no h dependence)
      accX[0] = zro; accX[1] = zro;
      #pragma unroll
      for (int kk = 0; kk < 8; ++kk){
        U8 a2, w0, w1;
        a2.h[0] = *(const short4v*)(xsrow + ((kk * 64 + 8 * g) ^ swA));
        a2.h[1] = *(const short4v*)(xsrow + ((kk * 64 + 32 + 8 * g) ^ swA));
        int cx = ((kk * 4 + g) ^ (l15 & 7)) << 4;
        w0.i = *(const int4v*)(wib0 + cx);
        w1.i = *(const int4v*)(wib1 + cx);
        accX[0] = __builtin_amdgcn_mfma_f32_16x16x32_bf16(a2.v, w0.v, accX[0], 0, 0, 0);
        accX[1] = __builtin_amdgcn_mfma_f32_16x16x32_bf16(a2.v, w1.v, accX[1], 0, 0, 0);
      }
      // ---- per-wave poll (lanes 1-3 of EVERY wave; wave proceeds when its
      // pollers pass — no cross-wave barrier needed before the reload)
      if (lane >= 1 && lane <= 3){
        int pl = lane - 1;
        int pslot = pl + (pl >= m ? 1 : 0);
        while (__hip_atomic_load(&flags[grp * 4 + pslot], __ATOMIC_RELAXED,
                                 __HIP_MEMORY_SCOPE_AGENT) <= t){}
      }
      // ---- reload h into HS (own wave's rows; barrier D orders vs matmul reads)
      {
        int bb = tid >> 6, cg = tid & 63;
        const unsigned long long* sp =
            (const unsigned long long*)(hb + bb * 256 + cg * 4);
        unsigned long long w0 = __hip_atomic_load(sp,     __ATOMIC_RELAXED, __HIP_MEMORY_SCOPE_AGENT);
        unsigned long long w1 = __hip_atomic_load(sp + 1, __ATOMIC_RELAXED, __HIP_MEMORY_SCOPE_AGENT);
        unsigned int u0 = (unsigned int)w0, u1 = (unsigned int)(w0 >> 32);
        unsigned int u2 = (unsigned int)w1, u3 = (unsigned int)(w1 >> 32);
        short4v hiv = { (short)(u0 & 0xffff), (short)(u1 & 0xffff),
                        (short)(u2 & 0xffff), (short)(u3 & 0xffff) };
        short4v lov = { (short)(u0 >> 16), (short)(u1 >> 16),
                        (short)(u2 >> 16), (short)(u3 >> 16) };
        int sw = (bb & 7) << 3;
        int cb = (cg * 8) ^ sw;
        *(short4v*)(HS + bb * 512 + cb) = hiv;
        *(short4v*)(HS + (bb + 8) * 512 + cb) = lov;
      }
      __syncthreads();                     // D: HS ready for next matmul
    }
  }
}

// ---------------------------------------------------------------------------
extern "C" void kernel_launch(void* const* d_in, const int* in_sizes, int n_in,
                              void* d_out, int out_size, void* d_ws, size_t ws_size,
                              hipStream_t stream){
  (void)in_sizes; (void)n_in; (void)out_size; (void)ws_size;
  const float* X   = (const float*)d_in[0];
  const float* Wq  = (const float*)d_in[1];
  const float* Wk  = (const float*)d_in[2];
  const float* Wv  = (const float*)d_in[3];
  const float* Wih = (const float*)d_in[4];
  const float* Whh = (const float*)d_in[5];
  const float* bih = (const float*)d_in[6];
  const float* bhh = (const float*)d_in[7];
  float* out = (float*)d_out;
  char* ws = (char*)d_ws;

  const size_t SZ = 33554432ULL;         // one (B,*,*) bf16 buffer
  unsigned short* p_q  = (unsigned short*)ws;
  unsigned short* p_k  = (unsigned short*)(ws + SZ);
  unsigned short* p_vt = (unsigned short*)(ws + 2 * SZ);
  unsigned short* p_xa = (unsigned short*)(ws + 3 * SZ);
  char* p = ws + 4 * SZ;
  unsigned short* p_wqb = (unsigned short*)p; p += 32768;
  unsigned short* p_wkb = (unsigned short*)p; p += 32768;
  unsigned short* p_wvb = (unsigned short*)p; p += 32768;
  unsigned short* p_whhf= (unsigned short*)p; p += 524288;
  unsigned short* p_wihf= (unsigned short*)p; p += 524288;
  float* p_bias = (float*)p; p += 4096;
  unsigned int* p_hbuf = (unsigned int*)p; p += 1048576;
  int* p_flags = (int*)p;

  k_prep3<<<128, 256, 0, stream>>>(Wq, Wk, Wv, Wih, Whh, bih, bhh,
                                   p_wqb, p_wkb, p_wvb, p_wihf, p_whhf,
                                   p_bias, p_flags);
  k_qkv2<<<1024, 256, 0, stream>>>(X, p_wqb, p_wkb, p_wvb, p_q, p_k, p_vt);
  k_attn2<<<dim3(2, 512), 512, 0, stream>>>(p_q, p_k, p_vt, p_xa);
  k_lstm9<<<256, 512, 0, stream>>>(p_xa, p_whhf, p_wihf, p_bias, out, p_hbuf, p_flags);
}